// Round 7
// baseline (666.927 us; speedup 1.0000x reference)
//
#include <hip/hip_runtime.h>
#include <math.h>

#define Nn 200000
#define NT 3125   // Nn / 64

typedef __attribute__((ext_vector_type(8))) short short8;
typedef __attribute__((ext_vector_type(16))) float floatx16;

// XOR swizzle for packed (dword) tiles: column-group g (4 dwords) XOR'd with (row & 7).
#define SWZ4(row, g) (((g) ^ ((row) & 7)) << 2)

// ---- bf16 split helpers (RNE) ----
__device__ __forceinline__ unsigned rnbf(float x) {
    unsigned u = __builtin_bit_cast(unsigned, x);
    return (u + 0x7fffu + ((u >> 16) & 1u)) >> 16;
}
__device__ __forceinline__ float asf(unsigned u) { return __builtin_bit_cast(float, u); }
// packed element: low16 = hi bf16, high16 = lo bf16
__device__ __forceinline__ unsigned packf(float x) {
    unsigned hb = rnbf(x);
    float fh = asf(hb << 16);
    unsigned lb = rnbf(x - fh);
    return hb | (lb << 16);
}
__device__ __forceinline__ void permsplit(const unsigned* e, short8& hi, short8& lo) {
    uint4 h, l;
    h.x = __builtin_amdgcn_perm(e[1], e[0], 0x05040100u);
    h.y = __builtin_amdgcn_perm(e[3], e[2], 0x05040100u);
    h.z = __builtin_amdgcn_perm(e[5], e[4], 0x05040100u);
    h.w = __builtin_amdgcn_perm(e[7], e[6], 0x05040100u);
    l.x = __builtin_amdgcn_perm(e[1], e[0], 0x07060302u);
    l.y = __builtin_amdgcn_perm(e[3], e[2], 0x07060302u);
    l.z = __builtin_amdgcn_perm(e[5], e[4], 0x07060302u);
    l.w = __builtin_amdgcn_perm(e[7], e[6], 0x07060302u);
    hi = __builtin_bit_cast(short8, h);
    lo = __builtin_bit_cast(short8, l);
}

// ---- PT partial += phi^T * h(64-row tile) via MFMA into this block's PTc copy.
// 256-thread (4-wave) packed version, used by lift_k only.
__device__ __forceinline__ void pt_accum(const unsigned* As, const unsigned* Ph,
                                         float* __restrict__ PTc_blk, int t) {
    int lane = t & 63, w = t >> 6;
    int ln = lane & 31, hw = lane >> 5;
    int j0 = w * 32;
    floatx16 ap;
#pragma unroll
    for (int i = 0; i < 16; i++) ap[i] = 0.f;
#pragma unroll
    for (int ks = 0; ks < 4; ks++) {
        unsigned pa[8], e[8];
#pragma unroll
        for (int j = 0; j < 8; j++) {
            int node = ks * 16 + 8 * hw + j;
            pa[j] = Ph[node * 32 + SWZ4(node, ln >> 2) + (ln & 3)];
            int col = j0 + ln;
            e[j] = As[node * 128 + SWZ4(node, col >> 2) + (col & 3)];
        }
        short8 a_hi, a_lo, b_hi, b_lo;
        permsplit(pa, a_hi, a_lo);
        permsplit(e, b_hi, b_lo);
        ap = __builtin_amdgcn_mfma_f32_32x32x16_bf16(a_hi, b_hi, ap, 0, 0, 0);
        ap = __builtin_amdgcn_mfma_f32_32x32x16_bf16(a_lo, b_hi, ap, 0, 0, 0);
        ap = __builtin_amdgcn_mfma_f32_32x32x16_bf16(a_hi, b_lo, ap, 0, 0, 0);
    }
#pragma unroll
    for (int r = 0; r < 16; r++) {
        int mode = (r & 3) + 8 * (r >> 2) + 4 * hw;
        if (mode < 20) unsafeAtomicAdd(&PTc_blk[mode * 128 + j0 + ln], ap[r]);
    }
}

// ---- 64-copy PT reduce: PT[j] = sum_c PTc[c][j]. grid 20 x 128.
__global__ void ptreduce_k(const float* __restrict__ PTc, float* __restrict__ PT) {
    int j = blockIdx.x * 128 + threadIdx.x;
    float s0 = 0.f, s1 = 0.f, s2 = 0.f, s3 = 0.f;
#pragma unroll
    for (int c = 0; c < 64; c += 4) {
        s0 += PTc[(size_t)c * 2560 + j];
        s1 += PTc[(size_t)(c + 1) * 2560 + j];
        s2 += PTc[(size_t)(c + 2) * 2560 + j];
        s3 += PTc[(size_t)(c + 3) * 2560 + j];
    }
    PT[j] = (s0 + s1) + (s2 + s3);
}

// ---- split lin_w (65536) + lower_w (512) into bf16 hi/lo. grid 258 x 256.
__global__ void wsplit_k(const float* __restrict__ lw, const float* __restrict__ low_w,
                         unsigned short* __restrict__ Wh, unsigned short* __restrict__ Wl,
                         unsigned short* __restrict__ LWh, unsigned short* __restrict__ LWl) {
    int i = blockIdx.x * 256 + threadIdx.x;
    float w;
    unsigned short *ph, *pl;
    int idx;
    if (i < 65536) { w = lw[i]; ph = Wh; pl = Wl; idx = i; }
    else           { w = low_w[i - 65536]; ph = LWh; pl = LWl; idx = i - 65536; }
    unsigned hb = rnbf(w);
    float fh = asf(hb << 16);
    unsigned lb = rnbf(w - fh);
    ph[idx] = (unsigned short)hb;
    pl[idx] = (unsigned short)lb;
}

// ---- lift (GEMM tile) + inline y-bias fold + fused PT0 partial scatter.
__global__ __launch_bounds__(256) void lift_k(const float* __restrict__ x,
                                              const float* __restrict__ pos,
                                              const float* __restrict__ phi,
                                              const float* __restrict__ lw,
                                              const float* __restrict__ lb,
                                              const float* __restrict__ yg,
                                              unsigned* __restrict__ hpk,
                                              float* __restrict__ PTc) {
    __shared__ union {
        struct { float xs[64][21]; float Wc[20][132]; } a;
        unsigned As[64 * 128];
    } sm;
    __shared__ unsigned Ph[64 * 32];
    int t = threadIdx.x;
    int n0 = blockIdx.x * 64;
    {
        int n = t >> 2, f4 = (t & 3) * 4;
        float4 xv = *(const float4*)(x + (size_t)(n0 + n) * 16 + f4);
        sm.a.xs[n][f4 + 0] = xv.x; sm.a.xs[n][f4 + 1] = xv.y;
        sm.a.xs[n][f4 + 2] = xv.z; sm.a.xs[n][f4 + 3] = xv.w;
    }
    if (t < 192) { int n = t / 3, d = t % 3; sm.a.xs[n][16 + d] = pos[(size_t)(n0 + n) * 3 + d]; }
    if (t < 64) sm.a.xs[t][19] = 1.f;
    for (int idx = t; idx < 2560; idx += 256) {
        int k = idx >> 7, j = idx & 127;
        float wv;
        if (k < 19) {
            wv = lw[j * 22 + k];
        } else {
            wv = lb[j] + yg[0] * lw[j * 22 + 19] + yg[1] * lw[j * 22 + 20]
                       + yg[2] * lw[j * 22 + 21];
        }
        sm.a.Wc[k][j] = wv;
    }
    for (int idx = t; idx < 2048; idx += 256) {
        int row = idx >> 5, kk = idx & 31;
        float pv = (kk < 20) ? phi[(size_t)(n0 + row) * 20 + kk] : 0.f;
        Ph[row * 32 + SWZ4(row, kk >> 2) + (kk & 3)] = packf(pv);
    }
    __syncthreads();
    int tx = t & 31, ty = t >> 5, i0 = tx * 4;
    float acc[8][4];
#pragma unroll
    for (int m = 0; m < 8; m++)
#pragma unroll
        for (int c = 0; c < 4; c++) acc[m][c] = 0.f;
#pragma unroll 4
    for (int k = 0; k < 20; k++) {
        float4 w = *(const float4*)&sm.a.Wc[k][i0];
#pragma unroll
        for (int m = 0; m < 8; m++) {
            float a = sm.a.xs[ty + 8 * m][k];
            acc[m][0] += a * w.x; acc[m][1] += a * w.y;
            acc[m][2] += a * w.z; acc[m][3] += a * w.w;
        }
    }
    __syncthreads();   // xs/Wc reads done before As overwrites the union
#pragma unroll
    for (int m = 0; m < 8; m++) {
        uint4 o;
        o.x = packf(acc[m][0]); o.y = packf(acc[m][1]);
        o.z = packf(acc[m][2]); o.w = packf(acc[m][3]);
        int row = ty + 8 * m;
        *(uint4*)&hpk[(size_t)(n0 + row) * 128 + i0] = o;
        *(uint4*)&sm.As[row * 128 + SWZ4(row, tx)] = o;
    }
    __syncthreads();
    pt_accum(sm.As, Ph, PTc + (size_t)(blockIdx.x & 63) * 2560, t);
}

// ---- G = phi^T phi  (20x20)
__global__ void gram_k(const float* __restrict__ phi, float* __restrict__ G) {
    __shared__ float ph[64 * 20];
    int t = threadIdx.x;
    int i0 = t / 20, j0 = t % 20;
    int p1 = t + 256;
    int i1 = p1 / 20, j1 = p1 % 20;
    float a0 = 0.f, a1 = 0.f;
    for (int tile = blockIdx.x; tile < NT; tile += gridDim.x) {
        const float* src = phi + tile * 1280;
        for (int idx = t; idx < 1280; idx += 256) ph[idx] = src[idx];
        __syncthreads();
        for (int n = 0; n < 64; n++) {
            const float* r = ph + n * 20;
            a0 += r[i0] * r[j0];
            if (p1 < 400) a1 += r[i1] * r[j1];
        }
        __syncthreads();
    }
    unsafeAtomicAdd(&G[t], a0);
    if (p1 < 400) unsafeAtomicAdd(&G[p1], a1);
}

// ---- Gauss-Jordan inverse of 20x20
__global__ void ginv_k(const float* __restrict__ G, float* __restrict__ Gi) {
    __shared__ float A[20][40];
    __shared__ float colp[20];
    __shared__ float piv;
    int t = threadIdx.x;
    for (int idx = t; idx < 400; idx += 64) {
        int r = idx / 20, c = idx % 20;
        A[r][c] = G[idx];
        A[r][c + 20] = (r == c) ? 1.f : 0.f;
    }
    __syncthreads();
    for (int p = 0; p < 20; p++) {
        if (t == 0) piv = 1.f / A[p][p];
        __syncthreads();
        for (int c = t; c < 40; c += 64) A[p][c] *= piv;
        __syncthreads();
        if (t < 20) colp[t] = A[t][p];
        __syncthreads();
        for (int e = t; e < 800; e += 64) {
            int r = e / 40, c = e % 40;
            if (r != p) A[r][c] -= colp[r] * A[p][c];
        }
        __syncthreads();
    }
    for (int idx = t; idx < 400; idx += 64) {
        int r = idx / 20, c = idx % 20;
        Gi[idx] = A[r][c + 20];
    }
}

// ---- v[k] = Gi[k] @ PT; RV = kernel[l][k] @ v[k]. Widened: grid (20, 8) x 256.
// Also zeros its 4 KB slice of PTc (replaces the per-layer memset dispatch).
__global__ void rv_k(const float* __restrict__ Gi, const float* __restrict__ PT,
                     const float* __restrict__ kern_l,
                     unsigned short* __restrict__ RVh, unsigned short* __restrict__ RVl,
                     float* __restrict__ ptz) {
    __shared__ __align__(16) float v[128];
    int k = blockIdx.x;
    int t = threadIdx.x;
    // zero this block's slice of PTc: 160 blocks x 1024 floats = 64 copies x 2560
    {
        float4 z = { 0.f, 0.f, 0.f, 0.f };
        int s = k * 8 + blockIdx.y;
        *(float4*)&ptz[(size_t)s * 1024 + t * 4] = z;
    }
    if (t < 128) {
        const float* gr = Gi + k * 20;
        float s = 0.f;
#pragma unroll
        for (int m = 0; m < 20; m++) s += gr[m] * PT[m * 128 + t];
        v[t] = s;
    }
    __syncthreads();
    int il = t >> 4, seg = t & 15;
    int i = blockIdx.y * 16 + il;
    const float* kr = kern_l + (size_t)(k * 128 + i) * 128 + seg * 8;
    const float* vk = v + seg * 8;
    float4 ka = *(const float4*)kr;
    float4 kb = *(const float4*)(kr + 4);
    float4 va = *(const float4*)vk;
    float4 vb = *(const float4*)(vk + 4);
    float acc = ka.x * va.x + ka.y * va.y + ka.z * va.z + ka.w * va.w
              + kb.x * vb.x + kb.y * vb.y + kb.z * vb.z + kb.w * vb.w;
    acc += __shfl_xor(acc, 8);
    acc += __shfl_xor(acc, 4);
    acc += __shfl_xor(acc, 2);
    acc += __shfl_xor(acc, 1);
    if (seg == 0) {
        unsigned hb = rnbf(acc);
        float fh = asf(hb << 16);
        unsigned lb = rnbf(acc - fh);
        RVh[i * 32 + k] = (unsigned short)hb;
        RVl[i * 32 + k] = (unsigned short)lb;
    }
}

// ---- MFMA update: 64-row tile, 512 threads (8 waves), 4 blocks/CU (160 KiB LDS).
// SPLIT-PLANE LDS: h and phi tiles as separate hi/lo ushort planes (direct b128 reads).
// Each wave owns one 32x32 output quadrant: rows (w>>2)*32, cols (w&3)*32.
// h = elu(h@W^T + phi@RV).
// l<3: IN-REGISTER PT — the wave's own p0 accumulator IS the PT B-fragment under
//      node permutation sigma(hw,j)=(j&3)+8*(j>>2)+4*hw (math verified in round 5);
//      A-side phi read in the same sigma order. No re-stash, 2 barriers instead of 4.
// l=3 (outp): re-stash + fused MFMA lower epilogue, skip h store.
__global__ __launch_bounds__(512, 8) void update_k(unsigned* __restrict__ hpk,
                                                   const float* __restrict__ phi,
                                                   const unsigned short* __restrict__ Wh,
                                                   const unsigned short* __restrict__ Wl,
                                                   const unsigned short* __restrict__ RVh,
                                                   const unsigned short* __restrict__ RVl,
                                                   float* __restrict__ ptn,
                                                   const unsigned short* __restrict__ LWh,
                                                   const unsigned short* __restrict__ LWl,
                                                   const float* __restrict__ low_b,
                                                   float* __restrict__ outp) {
    // 16384*2 + 4096*2 = 40960 B
    __shared__ __align__(16) unsigned short Ash[64 * 128];
    __shared__ __align__(16) unsigned short Asl[64 * 128];
    __shared__ __align__(16) unsigned short Phh[64 * 32];
    __shared__ __align__(16) unsigned short Phl[64 * 32];
    int t = threadIdx.x;
    int n0 = blockIdx.x * 64;
    // ---- stage packed h -> split planes (swizzled), packed phi -> split planes
    for (int idx = t; idx < 2048; idx += 512) {
        int row = idx >> 5, g = idx & 31;          // g: dword group of 4 cols
        uint4 v = *(const uint4*)(hpk + (size_t)(n0 + row) * 128 + g * 4);
        uint2 hv, lv;
        hv.x = __builtin_amdgcn_perm(v.y, v.x, 0x05040100u);
        hv.y = __builtin_amdgcn_perm(v.w, v.z, 0x05040100u);
        lv.x = __builtin_amdgcn_perm(v.y, v.x, 0x07060302u);
        lv.y = __builtin_amdgcn_perm(v.w, v.z, 0x07060302u);
        int base = row * 128 + (((g >> 1) ^ (row & 7)) << 3) + (g & 1) * 4;
        *(uint2*)&Ash[base] = hv;
        *(uint2*)&Asl[base] = lv;
    }
    for (int idx = t; idx < 2048; idx += 512) {
        int row = idx >> 5, kk = idx & 31;
        float pv = (kk < 20) ? phi[(size_t)(n0 + row) * 20 + kk] : 0.f;
        unsigned hb = rnbf(pv);
        float fh = asf(hb << 16);
        unsigned lb = rnbf(pv - fh);
        int pi = row * 32 + (((kk >> 3) ^ (row & 3)) << 3) + (kk & 7);
        Phh[pi] = (unsigned short)hb;
        Phl[pi] = (unsigned short)lb;
    }
    __syncthreads();

    int lane = t & 63, w = t >> 6;
    int ln = lane & 31, hw = lane >> 5;
    int r0 = (w >> 2) * 32, ct0 = (w & 3) * 32;
    int arow = r0 + ln;

    floatx16 acc;
#pragma unroll
    for (int i = 0; i < 16; i++) acc[i] = 0.f;

    const unsigned short* whp = Wh + (size_t)(ct0 + ln) * 128 + 8 * hw;
    const unsigned short* wlp = Wl + (size_t)(ct0 + ln) * 128 + 8 * hw;
    const unsigned short* ahb = Ash + arow * 128;
    const unsigned short* alb = Asl + arow * 128;
    int r7 = arow & 7;

    // ---- main K-loop (8 steps of 16): A-frags are direct b128 reads, zero perms
#pragma unroll
    for (int ks = 0; ks < 8; ks++) {
        int k0 = ks * 16;
        int gh = ((2 * ks + hw) ^ r7) << 3;
        short8 a_hi = __builtin_bit_cast(short8, *(const uint4*)(ahb + gh));
        short8 a_lo = __builtin_bit_cast(short8, *(const uint4*)(alb + gh));
        short8 bh = __builtin_bit_cast(short8, *(const uint4*)(whp + k0));
        short8 bl = __builtin_bit_cast(short8, *(const uint4*)(wlp + k0));
        acc = __builtin_amdgcn_mfma_f32_32x32x16_bf16(a_hi, bh, acc, 0, 0, 0);
        acc = __builtin_amdgcn_mfma_f32_32x32x16_bf16(a_lo, bh, acc, 0, 0, 0);
        acc = __builtin_amdgcn_mfma_f32_32x32x16_bf16(a_hi, bl, acc, 0, 0, 0);
    }

    // ---- phi @ RV: 2 more k-steps, direct b128 reads from phi planes
    const unsigned short* phb = Phh + arow * 32;
    const unsigned short* plb = Phl + arow * 32;
    int r3 = arow & 3;
#pragma unroll
    for (int ks = 0; ks < 2; ks++) {
        int k0 = ks * 16;
        int gp = ((2 * ks + hw) ^ r3) << 3;
        short8 a_hi = __builtin_bit_cast(short8, *(const uint4*)(phb + gp));
        short8 a_lo = __builtin_bit_cast(short8, *(const uint4*)(plb + gp));
        short8 bh = __builtin_bit_cast(short8, *(const uint4*)(RVh + (size_t)(ct0 + ln) * 32 + k0 + 8 * hw));
        short8 bl = __builtin_bit_cast(short8, *(const uint4*)(RVl + (size_t)(ct0 + ln) * 32 + k0 + 8 * hw));
        acc = __builtin_amdgcn_mfma_f32_32x32x16_bf16(a_hi, bh, acc, 0, 0, 0);
        acc = __builtin_amdgcn_mfma_f32_32x32x16_bf16(a_lo, bh, acc, 0, 0, 0);
        acc = __builtin_amdgcn_mfma_f32_32x32x16_bf16(a_hi, bl, acc, 0, 0, 0);
    }

    // ---- elu + pack; persist h unless this is the fused-output layer
    unsigned p0[16];
#pragma unroll
    for (int r = 0; r < 16; r++) {
        float v0 = acc[r];
        v0 = v0 > 0.f ? v0 : __expf(v0) - 1.f;
        p0[r] = packf(v0);
    }
    if (!outp) {
#pragma unroll
        for (int r = 0; r < 16; r++) {
            int row = (r & 3) + 8 * (r >> 2) + 4 * hw;
            hpk[(size_t)(n0 + r0 + row) * 128 + ct0 + ln] = p0[r];
        }
    }
    if (outp) {
        __syncthreads();   // all old-h LDS reads done
        // re-stash new h into the split planes (swizzled scalar u16 writes)
#pragma unroll
        for (int r = 0; r < 16; r++) {
            int row = r0 + (r & 3) + 8 * (r >> 2) + 4 * hw;
            int c0 = ct0 + ln;
            int si = row * 128 + (((c0 >> 3) ^ (row & 7)) << 3) + (c0 & 7);
            Ash[si] = (unsigned short)p0[r];
            Asl[si] = (unsigned short)(p0[r] >> 16);
        }
        __syncthreads();
        // MFMA lower: out = h @ lower_w^T + b. Waves 0-3 only:
        // r0o=(w>>1)*32 rows, kh=(w&1) k-half. B rows (outputs) 0-3, rows >=4 zero.
        float* scr = (float*)Phh;   // 1 KB scratch (phi planes dead at l=3)
        int r0o = (w >> 1) * 32, kh = w & 1;
        int arow2 = r0o + ln;
        const unsigned short* ah2 = Ash + arow2 * 128;
        const unsigned short* al2 = Asl + arow2 * 128;
        int rr7 = arow2 & 7;
        floatx16 ap;
#pragma unroll
        for (int i = 0; i < 16; i++) ap[i] = 0.f;
        if (w < 4) {
#pragma unroll
            for (int kk = 0; kk < 4; kk++) {
                int ks = kh * 4 + kk;
                int gh = ((2 * ks + hw) ^ rr7) << 3;
                short8 a_hi = __builtin_bit_cast(short8, *(const uint4*)(ah2 + gh));
                short8 a_lo = __builtin_bit_cast(short8, *(const uint4*)(al2 + gh));
                short8 bh = { 0, 0, 0, 0, 0, 0, 0, 0 };
                short8 bl = { 0, 0, 0, 0, 0, 0, 0, 0 };
                if (ln < 4) {
                    bh = __builtin_bit_cast(short8, *(const uint4*)(LWh + ln * 128 + ks * 16 + 8 * hw));
                    bl = __builtin_bit_cast(short8, *(const uint4*)(LWl + ln * 128 + ks * 16 + 8 * hw));
                }
                ap = __builtin_amdgcn_mfma_f32_32x32x16_bf16(a_hi, bh, ap, 0, 0, 0);
                ap = __builtin_amdgcn_mfma_f32_32x32x16_bf16(a_lo, bh, ap, 0, 0, 0);
                ap = __builtin_amdgcn_mfma_f32_32x32x16_bf16(a_hi, bl, ap, 0, 0, 0);
            }
        }
        if (w < 4 && kh == 1 && ln < 4) {
#pragma unroll
            for (int r = 0; r < 16; r++) {
                int row = (r & 3) + 8 * (r >> 2) + 4 * hw;
                scr[(w >> 1) * 128 + row * 4 + ln] = ap[r];
            }
        }
        __syncthreads();
        if (w < 4 && kh == 0 && ln < 4) {
            float b = low_b[ln];
#pragma unroll
            for (int r = 0; r < 16; r++) {
                int row = (r & 3) + 8 * (r >> 2) + 4 * hw;
                float s = ap[r] + scr[(w >> 1) * 128 + row * 4 + ln] + b;
                outp[(size_t)(n0 + r0o + row) * 4 + ln] = s;
            }
        }
    } else if (ptn) {
        // ---- in-register PT: B-fragment = own p0 (round-5-verified sigma math);
        // A-fragment = phi planes read in the same sigma node order.
        int nh = w >> 2;
        floatx16 ap;
#pragma unroll
        for (int i = 0; i < 16; i++) ap[i] = 0.f;
#pragma unroll
        for (int ks2 = 0; ks2 < 2; ks2++) {
            int pb = ks2 * 8;
            uint4 qh, ql;
            qh.x = __builtin_amdgcn_perm(p0[pb + 1], p0[pb + 0], 0x05040100u);
            qh.y = __builtin_amdgcn_perm(p0[pb + 3], p0[pb + 2], 0x05040100u);
            qh.z = __builtin_amdgcn_perm(p0[pb + 5], p0[pb + 4], 0x05040100u);
            qh.w = __builtin_amdgcn_perm(p0[pb + 7], p0[pb + 6], 0x05040100u);
            ql.x = __builtin_amdgcn_perm(p0[pb + 1], p0[pb + 0], 0x07060302u);
            ql.y = __builtin_amdgcn_perm(p0[pb + 3], p0[pb + 2], 0x07060302u);
            ql.z = __builtin_amdgcn_perm(p0[pb + 5], p0[pb + 4], 0x07060302u);
            ql.w = __builtin_amdgcn_perm(p0[pb + 7], p0[pb + 6], 0x07060302u);
            unsigned short ah8[8], al8[8];
#pragma unroll
            for (int j = 0; j < 8; j++) {
                int node = r0 + ks2 * 16 + (j & 3) + 8 * (j >> 2) + 4 * hw;
                int pi = node * 32 + (((ln >> 3) ^ (node & 3)) << 3) + (ln & 7);
                ah8[j] = Phh[pi];
                al8[j] = Phl[pi];
            }
            uint4 qa, qb;
            qa.x = (unsigned)ah8[0] | ((unsigned)ah8[1] << 16);
            qa.y = (unsigned)ah8[2] | ((unsigned)ah8[3] << 16);
            qa.z = (unsigned)ah8[4] | ((unsigned)ah8[5] << 16);
            qa.w = (unsigned)ah8[6] | ((unsigned)ah8[7] << 16);
            qb.x = (unsigned)al8[0] | ((unsigned)al8[1] << 16);
            qb.y = (unsigned)al8[2] | ((unsigned)al8[3] << 16);
            qb.z = (unsigned)al8[4] | ((unsigned)al8[5] << 16);
            qb.w = (unsigned)al8[6] | ((unsigned)al8[7] << 16);
            short8 a_hi = __builtin_bit_cast(short8, qa);
            short8 a_lo = __builtin_bit_cast(short8, qb);
            short8 b_hi = __builtin_bit_cast(short8, qh);
            short8 b_lo = __builtin_bit_cast(short8, ql);
            ap = __builtin_amdgcn_mfma_f32_32x32x16_bf16(a_hi, b_hi, ap, 0, 0, 0);
            ap = __builtin_amdgcn_mfma_f32_32x32x16_bf16(a_lo, b_hi, ap, 0, 0, 0);
            ap = __builtin_amdgcn_mfma_f32_32x32x16_bf16(a_hi, b_lo, ap, 0, 0, 0);
        }
        // combine node-halves (waves sharing ct0) through LDS, 1 atomic/elem
        __syncthreads();            // all main-loop/PT plane reads done before overlay
        float* PTs = (float*)Ash;   // 10 KB scratch overlay (Ash 16 KB, dead now)
        if (nh == 1) {
#pragma unroll
            for (int r = 0; r < 16; r++) {
                int mode = (r & 3) + 8 * (r >> 2) + 4 * hw;
                if (mode < 20) PTs[mode * 128 + ct0 + ln] = ap[r];
            }
        }
        __syncthreads();
        if (nh == 0) {
            float* blk = ptn + (size_t)(blockIdx.x & 63) * 2560;
#pragma unroll
            for (int r = 0; r < 16; r++) {
                int mode = (r & 3) + 8 * (r >> 2) + 4 * hw;
                if (mode < 20) {
                    int idx = mode * 128 + ct0 + ln;
                    unsafeAtomicAdd(&blk[idx], ap[r] + PTs[idx]);
                }
            }
        }
    }
}

extern "C" void kernel_launch(void* const* d_in, const int* in_sizes, int n_in,
                              void* d_out, int out_size, void* d_ws, size_t ws_size,
                              hipStream_t stream) {
    (void)in_sizes; (void)n_in; (void)out_size; (void)ws_size;
    const float* x       = (const float*)d_in[0];
    const float* pos     = (const float*)d_in[1];
    const float* y       = (const float*)d_in[2];
    const float* phi     = (const float*)d_in[3];
    const float* lift_w  = (const float*)d_in[4];
    const float* lift_b  = (const float*)d_in[5];
    const float* lin_w   = (const float*)d_in[6];
    const float* kern    = (const float*)d_in[7];
    const float* lower_w = (const float*)d_in[8];
    const float* lower_b = (const float*)d_in[9];
    float* out = (float*)d_out;

    char* ws = (char*)d_ws;
    unsigned* hpk = (unsigned*)ws;                       // 102,400,000 B
    size_t off = (size_t)Nn * 128 * 4;
    float* b2  = (float*)(ws + off);       off += 512;    // unused, layout kept
    float* G   = (float*)(ws + off);       off += 1600;
    float* Gi  = (float*)(ws + off);       off += 1600;
    off = (off + 15) & ~(size_t)15;
    float* PT  = (float*)(ws + off);       off += 10240;
    float* PTc = (float*)(ws + off);       off += 64 * 2560 * 4;   // 640 KB
    unsigned short* W_hi = (unsigned short*)(ws + off);  off += 131072;
    unsigned short* W_lo = (unsigned short*)(ws + off);  off += 131072;
    unsigned short* RVh  = (unsigned short*)(ws + off);  off += 8192;
    unsigned short* RVl  = (unsigned short*)(ws + off);  off += 8192;
    unsigned short* LWh  = (unsigned short*)(ws + off);  off += 1024;
    unsigned short* LWl  = (unsigned short*)(ws + off);  off += 1024;
    (void)b2;

    hipMemsetAsync(G, 0, 1600, stream);
    hipMemsetAsync(PTc, 0, 64 * 2560 * 4, stream);
    hipMemsetAsync(RVh, 0, 16384, stream);   // RVh+RVl adjacent
    wsplit_k<<<258, 256, 0, stream>>>(lin_w, lower_w, W_hi, W_lo, LWh, LWl);
    lift_k<<<NT, 256, 0, stream>>>(x, pos, phi, lift_w, lift_b, y, hpk, PTc);
    gram_k<<<256, 256, 0, stream>>>(phi, G);
    ginv_k<<<1, 64, 0, stream>>>(G, Gi);
    ptreduce_k<<<20, 128, 0, stream>>>(PTc, PT);

    for (int l = 0; l < 4; l++) {
        // rv also zeroes PTc for the coming update (ptreduce for prev layer is done)
        rv_k<<<dim3(20, 8), 256, 0, stream>>>(Gi, PT, kern + (size_t)l * 20 * 128 * 128,
                                              RVh, RVl, PTc);
        float* ptc = (l < 3) ? PTc : (float*)nullptr;
        update_k<<<NT, 512, 0, stream>>>(hpk, phi, W_hi + (size_t)l * 16384,
                                         W_lo + (size_t)l * 16384, RVh, RVl, ptc,
                                         LWh, LWl, lower_b,
                                         (l == 3) ? out : (float*)nullptr);
        if (ptc) ptreduce_k<<<20, 128, 0, stream>>>(PTc, PT);
    }
}

// Round 8
// 599.631 us; speedup vs baseline: 1.1122x; 1.1122x over previous
//
#include <hip/hip_runtime.h>
#include <math.h>

#define Nn 200000
#define NT 3125   // Nn / 64

typedef __attribute__((ext_vector_type(8))) short short8;
typedef __attribute__((ext_vector_type(16))) float floatx16;

// XOR swizzle for packed (dword) tiles: column-group g (4 dwords) XOR'd with (row & 7).
#define SWZ4(row, g) (((g) ^ ((row) & 7)) << 2)

// ---- bf16 split helpers (RNE) ----
__device__ __forceinline__ unsigned rnbf(float x) {
    unsigned u = __builtin_bit_cast(unsigned, x);
    return (u + 0x7fffu + ((u >> 16) & 1u)) >> 16;
}
__device__ __forceinline__ float asf(unsigned u) { return __builtin_bit_cast(float, u); }
// packed element: low16 = hi bf16, high16 = lo bf16
__device__ __forceinline__ unsigned packf(float x) {
    unsigned hb = rnbf(x);
    float fh = asf(hb << 16);
    unsigned lb = rnbf(x - fh);
    return hb | (lb << 16);
}
__device__ __forceinline__ void permsplit(const unsigned* e, short8& hi, short8& lo) {
    uint4 h, l;
    h.x = __builtin_amdgcn_perm(e[1], e[0], 0x05040100u);
    h.y = __builtin_amdgcn_perm(e[3], e[2], 0x05040100u);
    h.z = __builtin_amdgcn_perm(e[5], e[4], 0x05040100u);
    h.w = __builtin_amdgcn_perm(e[7], e[6], 0x05040100u);
    l.x = __builtin_amdgcn_perm(e[1], e[0], 0x07060302u);
    l.y = __builtin_amdgcn_perm(e[3], e[2], 0x07060302u);
    l.z = __builtin_amdgcn_perm(e[5], e[4], 0x07060302u);
    l.w = __builtin_amdgcn_perm(e[7], e[6], 0x07060302u);
    hi = __builtin_bit_cast(short8, h);
    lo = __builtin_bit_cast(short8, l);
}

// ---- 8-wave PT partial MFMA over packed swizzled tiles (round-3 verified):
// wave (w&3) -> col block, (w>>2) -> node half (K=32 each).
__device__ __forceinline__ void pt_mfma8(const unsigned* As, const unsigned* Ph,
                                         floatx16& ap, int t) {
    int lane = t & 63, w = t >> 6;
    int ln = lane & 31, hw = lane >> 5;
    int j0 = (w & 3) * 32;
    int nh = w >> 2;
#pragma unroll
    for (int i = 0; i < 16; i++) ap[i] = 0.f;
#pragma unroll
    for (int ks2 = 0; ks2 < 2; ks2++) {
        int ks = nh * 2 + ks2;
        unsigned pa[8], e[8];
#pragma unroll
        for (int j = 0; j < 8; j++) {
            int node = ks * 16 + 8 * hw + j;
            pa[j] = Ph[node * 32 + SWZ4(node, ln >> 2) + (ln & 3)];
            int col = j0 + ln;
            e[j] = As[node * 128 + SWZ4(node, col >> 2) + (col & 3)];
        }
        short8 a_hi, a_lo, b_hi, b_lo;
        permsplit(pa, a_hi, a_lo);
        permsplit(e, b_hi, b_lo);
        ap = __builtin_amdgcn_mfma_f32_32x32x16_bf16(a_hi, b_hi, ap, 0, 0, 0);
        ap = __builtin_amdgcn_mfma_f32_32x32x16_bf16(a_lo, b_hi, ap, 0, 0, 0);
        ap = __builtin_amdgcn_mfma_f32_32x32x16_bf16(a_hi, b_lo, ap, 0, 0, 0);
    }
}

// ---- 64-copy PT reduce: PT[j] = sum_c PTc[c][j]. grid 20 x 128.
__global__ void ptreduce_k(const float* __restrict__ PTc, float* __restrict__ PT) {
    int j = blockIdx.x * 128 + threadIdx.x;
    float s0 = 0.f, s1 = 0.f, s2 = 0.f, s3 = 0.f;
#pragma unroll
    for (int c = 0; c < 64; c += 4) {
        s0 += PTc[(size_t)c * 2560 + j];
        s1 += PTc[(size_t)(c + 1) * 2560 + j];
        s2 += PTc[(size_t)(c + 2) * 2560 + j];
        s3 += PTc[(size_t)(c + 3) * 2560 + j];
    }
    PT[j] = (s0 + s1) + (s2 + s3);
}

// ---- split lin_w (65536) + lower_w (512) into bf16 hi/lo. grid 258 x 256.
__global__ void wsplit_k(const float* __restrict__ lw, const float* __restrict__ low_w,
                         unsigned short* __restrict__ Wh, unsigned short* __restrict__ Wl,
                         unsigned short* __restrict__ LWh, unsigned short* __restrict__ LWl) {
    int i = blockIdx.x * 256 + threadIdx.x;
    float w;
    unsigned short *ph, *pl;
    int idx;
    if (i < 65536) { w = lw[i]; ph = Wh; pl = Wl; idx = i; }
    else           { w = low_w[i - 65536]; ph = LWh; pl = LWl; idx = i - 65536; }
    unsigned hb = rnbf(w);
    float fh = asf(hb << 16);
    unsigned lb = rnbf(w - fh);
    ph[idx] = (unsigned short)hb;
    pl[idx] = (unsigned short)lb;
}

// ---- lift (GEMM tile) + inline y-bias fold + fused PT0 partial.
// 512 threads (8 waves), 4 blocks/CU (160 KiB LDS) -> 32 waves/CU occupancy cap.
// PT tail: 8-wave pt_mfma8 + LDS combine of node halves -> 2560 atomics/block.
__global__ __launch_bounds__(512, 8) void lift_k(const float* __restrict__ x,
                                                 const float* __restrict__ pos,
                                                 const float* __restrict__ phi,
                                                 const float* __restrict__ lw,
                                                 const float* __restrict__ lb,
                                                 const float* __restrict__ yg,
                                                 unsigned* __restrict__ hpk,
                                                 float* __restrict__ PTc) {
    __shared__ union {
        struct { float xs[64][21]; float Wc[20][132]; } a;
        unsigned As[64 * 128];
    } sm;
    __shared__ unsigned Ph[64 * 32];
    int t = threadIdx.x;
    int n0 = blockIdx.x * 64;
    if (t < 256) {
        int n = t >> 2, f4 = (t & 3) * 4;
        float4 xv = *(const float4*)(x + (size_t)(n0 + n) * 16 + f4);
        sm.a.xs[n][f4 + 0] = xv.x; sm.a.xs[n][f4 + 1] = xv.y;
        sm.a.xs[n][f4 + 2] = xv.z; sm.a.xs[n][f4 + 3] = xv.w;
    }
    if (t < 192) { int n = t / 3, d = t % 3; sm.a.xs[n][16 + d] = pos[(size_t)(n0 + n) * 3 + d]; }
    if (t < 64) sm.a.xs[t][19] = 1.f;
    for (int idx = t; idx < 2560; idx += 512) {
        int k = idx >> 7, j = idx & 127;
        float wv;
        if (k < 19) {
            wv = lw[j * 22 + k];
        } else {
            wv = lb[j] + yg[0] * lw[j * 22 + 19] + yg[1] * lw[j * 22 + 20]
                       + yg[2] * lw[j * 22 + 21];
        }
        sm.a.Wc[k][j] = wv;
    }
    for (int idx = t; idx < 2048; idx += 512) {
        int row = idx >> 5, kk = idx & 31;
        float pv = (kk < 20) ? phi[(size_t)(n0 + row) * 20 + kk] : 0.f;
        Ph[row * 32 + SWZ4(row, kk >> 2) + (kk & 3)] = packf(pv);
    }
    __syncthreads();
    // GEMM: 512 threads, each 4 rows (ty + 16*m) x 4 cols (tx*4..+3)
    int tx = t & 31, ty = t >> 5, i0 = tx * 4;
    float acc[4][4];
#pragma unroll
    for (int m = 0; m < 4; m++)
#pragma unroll
        for (int c = 0; c < 4; c++) acc[m][c] = 0.f;
#pragma unroll 4
    for (int k = 0; k < 20; k++) {
        float4 w = *(const float4*)&sm.a.Wc[k][i0];
#pragma unroll
        for (int m = 0; m < 4; m++) {
            float a = sm.a.xs[ty + 16 * m][k];
            acc[m][0] += a * w.x; acc[m][1] += a * w.y;
            acc[m][2] += a * w.z; acc[m][3] += a * w.w;
        }
    }
    __syncthreads();   // xs/Wc reads done before As overwrites the union
#pragma unroll
    for (int m = 0; m < 4; m++) {
        uint4 o;
        o.x = packf(acc[m][0]); o.y = packf(acc[m][1]);
        o.z = packf(acc[m][2]); o.w = packf(acc[m][3]);
        int row = ty + 16 * m;
        *(uint4*)&hpk[(size_t)(n0 + row) * 128 + i0] = o;
        *(uint4*)&sm.As[row * 128 + SWZ4(row, tx)] = o;
    }
    __syncthreads();
    floatx16 ap;
    pt_mfma8(sm.As, Ph, ap, t);
    int lane = t & 63, w = t >> 6;
    int ln = lane & 31, hw = lane >> 5;
    int j0 = (w & 3) * 32, nh = w >> 2;
    __syncthreads();            // all As/Ph reads done before overlay
    float* PTs = (float*)sm.As; // 10 KB scratch overlay (As dead now)
    if (nh == 1) {
#pragma unroll
        for (int r = 0; r < 16; r++) {
            int mode = (r & 3) + 8 * (r >> 2) + 4 * hw;
            if (mode < 20) PTs[mode * 128 + j0 + ln] = ap[r];
        }
    }
    __syncthreads();
    if (nh == 0) {
        float* blk = PTc + (size_t)(blockIdx.x & 63) * 2560;
#pragma unroll
        for (int r = 0; r < 16; r++) {
            int mode = (r & 3) + 8 * (r >> 2) + 4 * hw;
            if (mode < 20) {
                int idx = mode * 128 + j0 + ln;
                unsafeAtomicAdd(&blk[idx], ap[r] + PTs[idx]);
            }
        }
    }
}

// ---- G = phi^T phi  (20x20)
__global__ void gram_k(const float* __restrict__ phi, float* __restrict__ G) {
    __shared__ float ph[64 * 20];
    int t = threadIdx.x;
    int i0 = t / 20, j0 = t % 20;
    int p1 = t + 256;
    int i1 = p1 / 20, j1 = p1 % 20;
    float a0 = 0.f, a1 = 0.f;
    for (int tile = blockIdx.x; tile < NT; tile += gridDim.x) {
        const float* src = phi + tile * 1280;
        for (int idx = t; idx < 1280; idx += 256) ph[idx] = src[idx];
        __syncthreads();
        for (int n = 0; n < 64; n++) {
            const float* r = ph + n * 20;
            a0 += r[i0] * r[j0];
            if (p1 < 400) a1 += r[i1] * r[j1];
        }
        __syncthreads();
    }
    unsafeAtomicAdd(&G[t], a0);
    if (p1 < 400) unsafeAtomicAdd(&G[p1], a1);
}

// ---- Gauss-Jordan inverse of 20x20
__global__ void ginv_k(const float* __restrict__ G, float* __restrict__ Gi) {
    __shared__ float A[20][40];
    __shared__ float colp[20];
    __shared__ float piv;
    int t = threadIdx.x;
    for (int idx = t; idx < 400; idx += 64) {
        int r = idx / 20, c = idx % 20;
        A[r][c] = G[idx];
        A[r][c + 20] = (r == c) ? 1.f : 0.f;
    }
    __syncthreads();
    for (int p = 0; p < 20; p++) {
        if (t == 0) piv = 1.f / A[p][p];
        __syncthreads();
        for (int c = t; c < 40; c += 64) A[p][c] *= piv;
        __syncthreads();
        if (t < 20) colp[t] = A[t][p];
        __syncthreads();
        for (int e = t; e < 800; e += 64) {
            int r = e / 40, c = e % 40;
            if (r != p) A[r][c] -= colp[r] * A[p][c];
        }
        __syncthreads();
    }
    for (int idx = t; idx < 400; idx += 64) {
        int r = idx / 20, c = idx % 20;
        Gi[idx] = A[r][c + 20];
    }
}

// ---- v[k] = Gi[k] @ PT; RV = kernel[l][k] @ v[k]. Widened: grid (20, 8) x 256.
// Also zeros its 4 KB slice of PTc (replaces the per-layer memset dispatch).
__global__ void rv_k(const float* __restrict__ Gi, const float* __restrict__ PT,
                     const float* __restrict__ kern_l,
                     unsigned short* __restrict__ RVh, unsigned short* __restrict__ RVl,
                     float* __restrict__ ptz) {
    __shared__ __align__(16) float v[128];
    int k = blockIdx.x;
    int t = threadIdx.x;
    // zero this block's slice of PTc: 160 blocks x 1024 floats = 64 copies x 2560
    {
        float4 z = { 0.f, 0.f, 0.f, 0.f };
        int s = k * 8 + blockIdx.y;
        *(float4*)&ptz[(size_t)s * 1024 + t * 4] = z;
    }
    if (t < 128) {
        const float* gr = Gi + k * 20;
        float s = 0.f;
#pragma unroll
        for (int m = 0; m < 20; m++) s += gr[m] * PT[m * 128 + t];
        v[t] = s;
    }
    __syncthreads();
    int il = t >> 4, seg = t & 15;
    int i = blockIdx.y * 16 + il;
    const float* kr = kern_l + (size_t)(k * 128 + i) * 128 + seg * 8;
    const float* vk = v + seg * 8;
    float4 ka = *(const float4*)kr;
    float4 kb = *(const float4*)(kr + 4);
    float4 va = *(const float4*)vk;
    float4 vb = *(const float4*)(vk + 4);
    float acc = ka.x * va.x + ka.y * va.y + ka.z * va.z + ka.w * va.w
              + kb.x * vb.x + kb.y * vb.y + kb.z * vb.z + kb.w * vb.w;
    acc += __shfl_xor(acc, 8);
    acc += __shfl_xor(acc, 4);
    acc += __shfl_xor(acc, 2);
    acc += __shfl_xor(acc, 1);
    if (seg == 0) {
        unsigned hb = rnbf(acc);
        float fh = asf(hb << 16);
        unsigned lb = rnbf(acc - fh);
        RVh[i * 32 + k] = (unsigned short)hb;
        RVl[i * 32 + k] = (unsigned short)lb;
    }
}

// ---- MFMA update (round-6 verified): 64-row tile, 512 threads, 4 blocks/CU.
// SPLIT-PLANE LDS: h and phi tiles as separate hi/lo ushort planes (direct b128 reads).
// Each wave owns one 32x32 output quadrant: rows (w>>2)*32, cols (w&3)*32.
// h = elu(h@W^T + phi@RV). l<3: LDS re-stash + split-plane PT + LDS half-combine.
// l=3 (outp): re-stash + fused MFMA lower epilogue, skip h store.
__global__ __launch_bounds__(512, 8) void update_k(unsigned* __restrict__ hpk,
                                                   const float* __restrict__ phi,
                                                   const unsigned short* __restrict__ Wh,
                                                   const unsigned short* __restrict__ Wl,
                                                   const unsigned short* __restrict__ RVh,
                                                   const unsigned short* __restrict__ RVl,
                                                   float* __restrict__ ptn,
                                                   const unsigned short* __restrict__ LWh,
                                                   const unsigned short* __restrict__ LWl,
                                                   const float* __restrict__ low_b,
                                                   float* __restrict__ outp) {
    // 16384*2 + 4096*2 = 40960 B
    __shared__ __align__(16) unsigned short Ash[64 * 128];
    __shared__ __align__(16) unsigned short Asl[64 * 128];
    __shared__ __align__(16) unsigned short Phh[64 * 32];
    __shared__ __align__(16) unsigned short Phl[64 * 32];
    int t = threadIdx.x;
    int n0 = blockIdx.x * 64;
    // ---- stage packed h -> split planes (swizzled), packed phi -> split planes
    for (int idx = t; idx < 2048; idx += 512) {
        int row = idx >> 5, g = idx & 31;          // g: dword group of 4 cols
        uint4 v = *(const uint4*)(hpk + (size_t)(n0 + row) * 128 + g * 4);
        uint2 hv, lv;
        hv.x = __builtin_amdgcn_perm(v.y, v.x, 0x05040100u);
        hv.y = __builtin_amdgcn_perm(v.w, v.z, 0x05040100u);
        lv.x = __builtin_amdgcn_perm(v.y, v.x, 0x07060302u);
        lv.y = __builtin_amdgcn_perm(v.w, v.z, 0x07060302u);
        int base = row * 128 + (((g >> 1) ^ (row & 7)) << 3) + (g & 1) * 4;
        *(uint2*)&Ash[base] = hv;
        *(uint2*)&Asl[base] = lv;
    }
    for (int idx = t; idx < 2048; idx += 512) {
        int row = idx >> 5, kk = idx & 31;
        float pv = (kk < 20) ? phi[(size_t)(n0 + row) * 20 + kk] : 0.f;
        unsigned hb = rnbf(pv);
        float fh = asf(hb << 16);
        unsigned lb = rnbf(pv - fh);
        int pi = row * 32 + (((kk >> 3) ^ (row & 3)) << 3) + (kk & 7);
        Phh[pi] = (unsigned short)hb;
        Phl[pi] = (unsigned short)lb;
    }
    __syncthreads();

    int lane = t & 63, w = t >> 6;
    int ln = lane & 31, hw = lane >> 5;
    int r0 = (w >> 2) * 32, ct0 = (w & 3) * 32;
    int arow = r0 + ln;

    floatx16 acc;
#pragma unroll
    for (int i = 0; i < 16; i++) acc[i] = 0.f;

    const unsigned short* whp = Wh + (size_t)(ct0 + ln) * 128 + 8 * hw;
    const unsigned short* wlp = Wl + (size_t)(ct0 + ln) * 128 + 8 * hw;
    const unsigned short* ahb = Ash + arow * 128;
    const unsigned short* alb = Asl + arow * 128;
    int r7 = arow & 7;

    // ---- main K-loop (8 steps of 16): A-frags are direct b128 reads, zero perms
#pragma unroll
    for (int ks = 0; ks < 8; ks++) {
        int k0 = ks * 16;
        int gh = ((2 * ks + hw) ^ r7) << 3;
        short8 a_hi = __builtin_bit_cast(short8, *(const uint4*)(ahb + gh));
        short8 a_lo = __builtin_bit_cast(short8, *(const uint4*)(alb + gh));
        short8 bh = __builtin_bit_cast(short8, *(const uint4*)(whp + k0));
        short8 bl = __builtin_bit_cast(short8, *(const uint4*)(wlp + k0));
        acc = __builtin_amdgcn_mfma_f32_32x32x16_bf16(a_hi, bh, acc, 0, 0, 0);
        acc = __builtin_amdgcn_mfma_f32_32x32x16_bf16(a_lo, bh, acc, 0, 0, 0);
        acc = __builtin_amdgcn_mfma_f32_32x32x16_bf16(a_hi, bl, acc, 0, 0, 0);
    }

    // ---- phi @ RV: 2 more k-steps, direct b128 reads from phi planes
    const unsigned short* phb = Phh + arow * 32;
    const unsigned short* plb = Phl + arow * 32;
    int r3 = arow & 3;
#pragma unroll
    for (int ks = 0; ks < 2; ks++) {
        int k0 = ks * 16;
        int gp = ((2 * ks + hw) ^ r3) << 3;
        short8 a_hi = __builtin_bit_cast(short8, *(const uint4*)(phb + gp));
        short8 a_lo = __builtin_bit_cast(short8, *(const uint4*)(plb + gp));
        short8 bh = __builtin_bit_cast(short8, *(const uint4*)(RVh + (size_t)(ct0 + ln) * 32 + k0 + 8 * hw));
        short8 bl = __builtin_bit_cast(short8, *(const uint4*)(RVl + (size_t)(ct0 + ln) * 32 + k0 + 8 * hw));
        acc = __builtin_amdgcn_mfma_f32_32x32x16_bf16(a_hi, bh, acc, 0, 0, 0);
        acc = __builtin_amdgcn_mfma_f32_32x32x16_bf16(a_lo, bh, acc, 0, 0, 0);
        acc = __builtin_amdgcn_mfma_f32_32x32x16_bf16(a_hi, bl, acc, 0, 0, 0);
    }

    // ---- elu + pack; persist h unless this is the fused-output layer
    unsigned p0[16];
#pragma unroll
    for (int r = 0; r < 16; r++) {
        float v0 = acc[r];
        v0 = v0 > 0.f ? v0 : __expf(v0) - 1.f;
        p0[r] = packf(v0);
    }
    if (!outp) {
#pragma unroll
        for (int r = 0; r < 16; r++) {
            int row = (r & 3) + 8 * (r >> 2) + 4 * hw;
            hpk[(size_t)(n0 + r0 + row) * 128 + ct0 + ln] = p0[r];
        }
    }
    if (ptn || outp) {
        __syncthreads();   // all old-h LDS reads done
        // re-stash new h into the split planes (swizzled scalar u16 writes)
#pragma unroll
        for (int r = 0; r < 16; r++) {
            int row = r0 + (r & 3) + 8 * (r >> 2) + 4 * hw;
            int c0 = ct0 + ln;
            int si = row * 128 + (((c0 >> 3) ^ (row & 7)) << 3) + (c0 & 7);
            Ash[si] = (unsigned short)p0[r];
            Asl[si] = (unsigned short)(p0[r] >> 16);
        }
        __syncthreads();
        if (outp) {
            // MFMA lower: out = h @ lower_w^T + b. Waves 0-3 only:
            // r0o=(w>>1)*32 rows, kh=(w&1) k-half. B rows (outputs) 0-3, rows >=4 zero.
            float* scr = (float*)Phh;   // 1 KB scratch (phi planes dead at l=3)
            int r0o = (w >> 1) * 32, kh = w & 1;
            int arow2 = r0o + ln;
            const unsigned short* ah2 = Ash + arow2 * 128;
            const unsigned short* al2 = Asl + arow2 * 128;
            int rr7 = arow2 & 7;
            floatx16 ap;
#pragma unroll
            for (int i = 0; i < 16; i++) ap[i] = 0.f;
            if (w < 4) {
#pragma unroll
                for (int kk = 0; kk < 4; kk++) {
                    int ks = kh * 4 + kk;
                    int gh = ((2 * ks + hw) ^ rr7) << 3;
                    short8 a_hi = __builtin_bit_cast(short8, *(const uint4*)(ah2 + gh));
                    short8 a_lo = __builtin_bit_cast(short8, *(const uint4*)(al2 + gh));
                    short8 bh = { 0, 0, 0, 0, 0, 0, 0, 0 };
                    short8 bl = { 0, 0, 0, 0, 0, 0, 0, 0 };
                    if (ln < 4) {
                        bh = __builtin_bit_cast(short8, *(const uint4*)(LWh + ln * 128 + ks * 16 + 8 * hw));
                        bl = __builtin_bit_cast(short8, *(const uint4*)(LWl + ln * 128 + ks * 16 + 8 * hw));
                    }
                    ap = __builtin_amdgcn_mfma_f32_32x32x16_bf16(a_hi, bh, ap, 0, 0, 0);
                    ap = __builtin_amdgcn_mfma_f32_32x32x16_bf16(a_lo, bh, ap, 0, 0, 0);
                    ap = __builtin_amdgcn_mfma_f32_32x32x16_bf16(a_hi, bl, ap, 0, 0, 0);
                }
            }
            if (w < 4 && kh == 1 && ln < 4) {
#pragma unroll
                for (int r = 0; r < 16; r++) {
                    int row = (r & 3) + 8 * (r >> 2) + 4 * hw;
                    scr[(w >> 1) * 128 + row * 4 + ln] = ap[r];
                }
            }
            __syncthreads();
            if (w < 4 && kh == 0 && ln < 4) {
                float b = low_b[ln];
#pragma unroll
                for (int r = 0; r < 16; r++) {
                    int row = (r & 3) + 8 * (r >> 2) + 4 * hw;
                    float s = ap[r] + scr[(w >> 1) * 128 + row * 4 + ln] + b;
                    outp[(size_t)(n0 + r0o + row) * 4 + ln] = s;
                }
            }
        } else {
            // ---- PT partial from split planes: wave (w&3) col block, (w>>2) node half
            int j0 = (w & 3) * 32, nh = w >> 2;
            floatx16 ap;
#pragma unroll
            for (int i = 0; i < 16; i++) ap[i] = 0.f;
#pragma unroll
            for (int ks2 = 0; ks2 < 2; ks2++) {
                int ks = nh * 2 + ks2;
                unsigned short ah[8], al[8], bh[8], bl[8];
#pragma unroll
                for (int j = 0; j < 8; j++) {
                    int node = ks * 16 + 8 * hw + j;
                    int pi = node * 32 + (((ln >> 3) ^ (node & 3)) << 3) + (ln & 7);
                    ah[j] = Phh[pi]; al[j] = Phl[pi];
                    int col = j0 + ln;
                    int si = node * 128 + (((col >> 3) ^ (node & 7)) << 3) + (col & 7);
                    bh[j] = Ash[si]; bl[j] = Asl[si];
                }
                uint4 qa, qb, qc, qd;
                qa.x = (unsigned)ah[0] | ((unsigned)ah[1] << 16);
                qa.y = (unsigned)ah[2] | ((unsigned)ah[3] << 16);
                qa.z = (unsigned)ah[4] | ((unsigned)ah[5] << 16);
                qa.w = (unsigned)ah[6] | ((unsigned)ah[7] << 16);
                qb.x = (unsigned)al[0] | ((unsigned)al[1] << 16);
                qb.y = (unsigned)al[2] | ((unsigned)al[3] << 16);
                qb.z = (unsigned)al[4] | ((unsigned)al[5] << 16);
                qb.w = (unsigned)al[6] | ((unsigned)al[7] << 16);
                qc.x = (unsigned)bh[0] | ((unsigned)bh[1] << 16);
                qc.y = (unsigned)bh[2] | ((unsigned)bh[3] << 16);
                qc.z = (unsigned)bh[4] | ((unsigned)bh[5] << 16);
                qc.w = (unsigned)bh[6] | ((unsigned)bh[7] << 16);
                qd.x = (unsigned)bl[0] | ((unsigned)bl[1] << 16);
                qd.y = (unsigned)bl[2] | ((unsigned)bl[3] << 16);
                qd.z = (unsigned)bl[4] | ((unsigned)bl[5] << 16);
                qd.w = (unsigned)bl[6] | ((unsigned)bl[7] << 16);
                short8 a_hi = __builtin_bit_cast(short8, qa);
                short8 a_lo = __builtin_bit_cast(short8, qb);
                short8 b_hi = __builtin_bit_cast(short8, qc);
                short8 b_lo = __builtin_bit_cast(short8, qd);
                ap = __builtin_amdgcn_mfma_f32_32x32x16_bf16(a_hi, b_hi, ap, 0, 0, 0);
                ap = __builtin_amdgcn_mfma_f32_32x32x16_bf16(a_lo, b_hi, ap, 0, 0, 0);
                ap = __builtin_amdgcn_mfma_f32_32x32x16_bf16(a_hi, b_lo, ap, 0, 0, 0);
            }
            __syncthreads();            // all plane reads done before overlay
            float* PTs = (float*)Ash;   // 10 KB scratch overlay (Ash 16 KB, dead now)
            if (nh == 1) {
#pragma unroll
                for (int r = 0; r < 16; r++) {
                    int mode = (r & 3) + 8 * (r >> 2) + 4 * hw;
                    if (mode < 20) PTs[mode * 128 + j0 + ln] = ap[r];
                }
            }
            __syncthreads();
            if (nh == 0) {
                float* blk = ptn + (size_t)(blockIdx.x & 63) * 2560;
#pragma unroll
                for (int r = 0; r < 16; r++) {
                    int mode = (r & 3) + 8 * (r >> 2) + 4 * hw;
                    if (mode < 20) {
                        int idx = mode * 128 + j0 + ln;
                        unsafeAtomicAdd(&blk[idx], ap[r] + PTs[idx]);
                    }
                }
            }
        }
    }
}

extern "C" void kernel_launch(void* const* d_in, const int* in_sizes, int n_in,
                              void* d_out, int out_size, void* d_ws, size_t ws_size,
                              hipStream_t stream) {
    (void)in_sizes; (void)n_in; (void)out_size; (void)ws_size;
    const float* x       = (const float*)d_in[0];
    const float* pos     = (const float*)d_in[1];
    const float* y       = (const float*)d_in[2];
    const float* phi     = (const float*)d_in[3];
    const float* lift_w  = (const float*)d_in[4];
    const float* lift_b  = (const float*)d_in[5];
    const float* lin_w   = (const float*)d_in[6];
    const float* kern    = (const float*)d_in[7];
    const float* lower_w = (const float*)d_in[8];
    const float* lower_b = (const float*)d_in[9];
    float* out = (float*)d_out;

    char* ws = (char*)d_ws;
    unsigned* hpk = (unsigned*)ws;                       // 102,400,000 B
    size_t off = (size_t)Nn * 128 * 4;
    float* b2  = (float*)(ws + off);       off += 512;    // unused, layout kept
    float* G   = (float*)(ws + off);       off += 1600;
    float* Gi  = (float*)(ws + off);       off += 1600;
    off = (off + 15) & ~(size_t)15;
    float* PT  = (float*)(ws + off);       off += 10240;
    float* PTc = (float*)(ws + off);       off += 64 * 2560 * 4;   // 640 KB
    unsigned short* W_hi = (unsigned short*)(ws + off);  off += 131072;
    unsigned short* W_lo = (unsigned short*)(ws + off);  off += 131072;
    unsigned short* RVh  = (unsigned short*)(ws + off);  off += 8192;
    unsigned short* RVl  = (unsigned short*)(ws + off);  off += 8192;
    unsigned short* LWh  = (unsigned short*)(ws + off);  off += 1024;
    unsigned short* LWl  = (unsigned short*)(ws + off);  off += 1024;
    (void)b2;

    hipMemsetAsync(G, 0, 1600, stream);
    hipMemsetAsync(PTc, 0, 64 * 2560 * 4, stream);
    hipMemsetAsync(RVh, 0, 16384, stream);   // RVh+RVl adjacent
    wsplit_k<<<258, 256, 0, stream>>>(lin_w, lower_w, W_hi, W_lo, LWh, LWl);
    lift_k<<<NT, 512, 0, stream>>>(x, pos, phi, lift_w, lift_b, y, hpk, PTc);
    gram_k<<<256, 256, 0, stream>>>(phi, G);
    ginv_k<<<1, 64, 0, stream>>>(G, Gi);
    ptreduce_k<<<20, 128, 0, stream>>>(PTc, PT);

    for (int l = 0; l < 4; l++) {
        // rv also zeroes PTc for the coming update (ptreduce for prev layer is done)
        rv_k<<<dim3(20, 8), 256, 0, stream>>>(Gi, PT, kern + (size_t)l * 20 * 128 * 128,
                                              RVh, RVl, PTc);
        float* ptc = (l < 3) ? PTc : (float*)nullptr;
        update_k<<<NT, 512, 0, stream>>>(hpk, phi, W_hi + (size_t)l * 16384,
                                         W_lo + (size_t)l * 16384, RVh, RVl, ptc,
                                         LWh, LWl, lower_b,
                                         (l == 3) ? out : (float*)nullptr);
        if (ptc) ptreduce_k<<<20, 128, 0, stream>>>(PTc, PT);
    }
}

// Round 10
// 587.934 us; speedup vs baseline: 1.1344x; 1.0199x over previous
//
#include <hip/hip_runtime.h>
#include <math.h>

#define Nn 200000
#define NT 3125   // Nn / 64

typedef __attribute__((ext_vector_type(8))) short short8;
typedef __attribute__((ext_vector_type(16))) float floatx16;

// XOR swizzle for packed (dword) tiles: column-group g (4 dwords) XOR'd with (row & 7).
#define SWZ4(row, g) (((g) ^ ((row) & 7)) << 2)

// ---- bf16 split helpers (RNE) ----
__device__ __forceinline__ unsigned rnbf(float x) {
    unsigned u = __builtin_bit_cast(unsigned, x);
    return (u + 0x7fffu + ((u >> 16) & 1u)) >> 16;
}
__device__ __forceinline__ float asf(unsigned u) { return __builtin_bit_cast(float, u); }
// packed element: low16 = hi bf16, high16 = lo bf16
__device__ __forceinline__ unsigned packf(float x) {
    unsigned hb = rnbf(x);
    float fh = asf(hb << 16);
    unsigned lb = rnbf(x - fh);
    return hb | (lb << 16);
}
__device__ __forceinline__ void permsplit(const unsigned* e, short8& hi, short8& lo) {
    uint4 h, l;
    h.x = __builtin_amdgcn_perm(e[1], e[0], 0x05040100u);
    h.y = __builtin_amdgcn_perm(e[3], e[2], 0x05040100u);
    h.z = __builtin_amdgcn_perm(e[5], e[4], 0x05040100u);
    h.w = __builtin_amdgcn_perm(e[7], e[6], 0x05040100u);
    l.x = __builtin_amdgcn_perm(e[1], e[0], 0x07060302u);
    l.y = __builtin_amdgcn_perm(e[3], e[2], 0x07060302u);
    l.z = __builtin_amdgcn_perm(e[5], e[4], 0x07060302u);
    l.w = __builtin_amdgcn_perm(e[7], e[6], 0x07060302u);
    hi = __builtin_bit_cast(short8, h);
    lo = __builtin_bit_cast(short8, l);
}

// ---- 8-wave PT partial MFMA over packed swizzled tiles (round-3 verified):
// wave (w&3) -> col block, (w>>2) -> node half (K=32 each). Used by lift_k.
__device__ __forceinline__ void pt_mfma8(const unsigned* As, const unsigned* Ph,
                                         floatx16& ap, int t) {
    int lane = t & 63, w = t >> 6;
    int ln = lane & 31, hw = lane >> 5;
    int j0 = (w & 3) * 32;
    int nh = w >> 2;
#pragma unroll
    for (int i = 0; i < 16; i++) ap[i] = 0.f;
#pragma unroll
    for (int ks2 = 0; ks2 < 2; ks2++) {
        int ks = nh * 2 + ks2;
        unsigned pa[8], e[8];
#pragma unroll
        for (int j = 0; j < 8; j++) {
            int node = ks * 16 + 8 * hw + j;
            pa[j] = Ph[node * 32 + SWZ4(node, ln >> 2) + (ln & 3)];
            int col = j0 + ln;
            e[j] = As[node * 128 + SWZ4(node, col >> 2) + (col & 3)];
        }
        short8 a_hi, a_lo, b_hi, b_lo;
        permsplit(pa, a_hi, a_lo);
        permsplit(e, b_hi, b_lo);
        ap = __builtin_amdgcn_mfma_f32_32x32x16_bf16(a_hi, b_hi, ap, 0, 0, 0);
        ap = __builtin_amdgcn_mfma_f32_32x32x16_bf16(a_lo, b_hi, ap, 0, 0, 0);
        ap = __builtin_amdgcn_mfma_f32_32x32x16_bf16(a_hi, b_lo, ap, 0, 0, 0);
    }
}

// ---- 64-copy PT reduce: PT[j] = sum_c PTc[c][j]. grid 20 x 128.
__global__ void ptreduce_k(const float* __restrict__ PTc, float* __restrict__ PT) {
    int j = blockIdx.x * 128 + threadIdx.x;
    float s0 = 0.f, s1 = 0.f, s2 = 0.f, s3 = 0.f;
#pragma unroll
    for (int c = 0; c < 64; c += 4) {
        s0 += PTc[(size_t)c * 2560 + j];
        s1 += PTc[(size_t)(c + 1) * 2560 + j];
        s2 += PTc[(size_t)(c + 2) * 2560 + j];
        s3 += PTc[(size_t)(c + 3) * 2560 + j];
    }
    PT[j] = (s0 + s1) + (s2 + s3);
}

// ---- split lin_w (65536) + lower_w (512) into bf16 hi/lo. grid 258 x 256.
__global__ void wsplit_k(const float* __restrict__ lw, const float* __restrict__ low_w,
                         unsigned short* __restrict__ Wh, unsigned short* __restrict__ Wl,
                         unsigned short* __restrict__ LWh, unsigned short* __restrict__ LWl) {
    int i = blockIdx.x * 256 + threadIdx.x;
    float w;
    unsigned short *ph, *pl;
    int idx;
    if (i < 65536) { w = lw[i]; ph = Wh; pl = Wl; idx = i; }
    else           { w = low_w[i - 65536]; ph = LWh; pl = LWl; idx = i - 65536; }
    unsigned hb = rnbf(w);
    float fh = asf(hb << 16);
    unsigned lb = rnbf(w - fh);
    ph[idx] = (unsigned short)hb;
    pl[idx] = (unsigned short)lb;
}

// ---- lift (GEMM tile) + inline y-bias fold + fused PT0 partial.
// 512 threads (8 waves), 4 blocks/CU (160 KiB LDS) -> 32 waves/CU occupancy cap.
// PT tail: 8-wave pt_mfma8 + LDS combine of node halves -> 2560 atomics/block.
__global__ __launch_bounds__(512, 8) void lift_k(const float* __restrict__ x,
                                                 const float* __restrict__ pos,
                                                 const float* __restrict__ phi,
                                                 const float* __restrict__ lw,
                                                 const float* __restrict__ lb,
                                                 const float* __restrict__ yg,
                                                 unsigned* __restrict__ hpk,
                                                 float* __restrict__ PTc) {
    __shared__ union {
        struct { float xs[64][21]; float Wc[20][132]; } a;
        unsigned As[64 * 128];
    } sm;
    __shared__ unsigned Ph[64 * 32];
    int t = threadIdx.x;
    int n0 = blockIdx.x * 64;
    if (t < 256) {
        int n = t >> 2, f4 = (t & 3) * 4;
        float4 xv = *(const float4*)(x + (size_t)(n0 + n) * 16 + f4);
        sm.a.xs[n][f4 + 0] = xv.x; sm.a.xs[n][f4 + 1] = xv.y;
        sm.a.xs[n][f4 + 2] = xv.z; sm.a.xs[n][f4 + 3] = xv.w;
    }
    if (t < 192) { int n = t / 3, d = t % 3; sm.a.xs[n][16 + d] = pos[(size_t)(n0 + n) * 3 + d]; }
    if (t < 64) sm.a.xs[t][19] = 1.f;
    for (int idx = t; idx < 2560; idx += 512) {
        int k = idx >> 7, j = idx & 127;
        float wv;
        if (k < 19) {
            wv = lw[j * 22 + k];
        } else {
            wv = lb[j] + yg[0] * lw[j * 22 + 19] + yg[1] * lw[j * 22 + 20]
                       + yg[2] * lw[j * 22 + 21];
        }
        sm.a.Wc[k][j] = wv;
    }
    for (int idx = t; idx < 2048; idx += 512) {
        int row = idx >> 5, kk = idx & 31;
        float pv = (kk < 20) ? phi[(size_t)(n0 + row) * 20 + kk] : 0.f;
        Ph[row * 32 + SWZ4(row, kk >> 2) + (kk & 3)] = packf(pv);
    }
    __syncthreads();
    // GEMM: 512 threads, each 4 rows (ty + 16*m) x 4 cols (tx*4..+3)
    int tx = t & 31, ty = t >> 5, i0 = tx * 4;
    float acc[4][4];
#pragma unroll
    for (int m = 0; m < 4; m++)
#pragma unroll
        for (int c = 0; c < 4; c++) acc[m][c] = 0.f;
#pragma unroll 4
    for (int k = 0; k < 20; k++) {
        float4 w = *(const float4*)&sm.a.Wc[k][i0];
#pragma unroll
        for (int m = 0; m < 4; m++) {
            float a = sm.a.xs[ty + 16 * m][k];
            acc[m][0] += a * w.x; acc[m][1] += a * w.y;
            acc[m][2] += a * w.z; acc[m][3] += a * w.w;
        }
    }
    __syncthreads();   // xs/Wc reads done before As overwrites the union
#pragma unroll
    for (int m = 0; m < 4; m++) {
        uint4 o;
        o.x = packf(acc[m][0]); o.y = packf(acc[m][1]);
        o.z = packf(acc[m][2]); o.w = packf(acc[m][3]);
        int row = ty + 16 * m;
        *(uint4*)&hpk[(size_t)(n0 + row) * 128 + i0] = o;
        *(uint4*)&sm.As[row * 128 + SWZ4(row, tx)] = o;
    }
    __syncthreads();
    floatx16 ap;
    pt_mfma8(sm.As, Ph, ap, t);
    int lane = t & 63, w = t >> 6;
    int ln = lane & 31, hw = lane >> 5;
    int j0 = (w & 3) * 32, nh = w >> 2;
    __syncthreads();            // all As/Ph reads done before overlay
    float* PTs = (float*)sm.As; // 10 KB scratch overlay (As dead now)
    if (nh == 1) {
#pragma unroll
        for (int r = 0; r < 16; r++) {
            int mode = (r & 3) + 8 * (r >> 2) + 4 * hw;
            if (mode < 20) PTs[mode * 128 + j0 + ln] = ap[r];
        }
    }
    __syncthreads();
    if (nh == 0) {
        float* blk = PTc + (size_t)(blockIdx.x & 63) * 2560;
#pragma unroll
        for (int r = 0; r < 16; r++) {
            int mode = (r & 3) + 8 * (r >> 2) + 4 * hw;
            if (mode < 20) {
                int idx = mode * 128 + j0 + ln;
                unsafeAtomicAdd(&blk[idx], ap[r] + PTs[idx]);
            }
        }
    }
}

// ---- G = phi^T phi  (20x20)
__global__ void gram_k(const float* __restrict__ phi, float* __restrict__ G) {
    __shared__ float ph[64 * 20];
    int t = threadIdx.x;
    int i0 = t / 20, j0 = t % 20;
    int p1 = t + 256;
    int i1 = p1 / 20, j1 = p1 % 20;
    float a0 = 0.f, a1 = 0.f;
    for (int tile = blockIdx.x; tile < NT; tile += gridDim.x) {
        const float* src = phi + tile * 1280;
        for (int idx = t; idx < 1280; idx += 256) ph[idx] = src[idx];
        __syncthreads();
        for (int n = 0; n < 64; n++) {
            const float* r = ph + n * 20;
            a0 += r[i0] * r[j0];
            if (p1 < 400) a1 += r[i1] * r[j1];
        }
        __syncthreads();
    }
    unsafeAtomicAdd(&G[t], a0);
    if (p1 < 400) unsafeAtomicAdd(&G[p1], a1);
}

// ---- Gauss-Jordan inverse of 20x20
__global__ void ginv_k(const float* __restrict__ G, float* __restrict__ Gi) {
    __shared__ float A[20][40];
    __shared__ float colp[20];
    __shared__ float piv;
    int t = threadIdx.x;
    for (int idx = t; idx < 400; idx += 64) {
        int r = idx / 20, c = idx % 20;
        A[r][c] = G[idx];
        A[r][c + 20] = (r == c) ? 1.f : 0.f;
    }
    __syncthreads();
    for (int p = 0; p < 20; p++) {
        if (t == 0) piv = 1.f / A[p][p];
        __syncthreads();
        for (int c = t; c < 40; c += 64) A[p][c] *= piv;
        __syncthreads();
        if (t < 20) colp[t] = A[t][p];
        __syncthreads();
        for (int e = t; e < 800; e += 64) {
            int r = e / 40, c = e % 40;
            if (r != p) A[r][c] -= colp[r] * A[p][c];
        }
        __syncthreads();
    }
    for (int idx = t; idx < 400; idx += 64) {
        int r = idx / 20, c = idx % 20;
        Gi[idx] = A[r][c + 20];
    }
}

// ---- v[k] = Gi[k] @ PT; RV = kernel[l][k] @ v[k]. Widened: grid (20, 8) x 256.
// kern loads hoisted ABOVE the zero/v phase so cold-HBM latency hides under it.
// Also zeros its 4 KB slice of PTc (replaces the per-layer memset dispatch).
__global__ void rv_k(const float* __restrict__ Gi, const float* __restrict__ PT,
                     const float* __restrict__ kern_l,
                     unsigned short* __restrict__ RVh, unsigned short* __restrict__ RVl,
                     float* __restrict__ ptz) {
    __shared__ __align__(16) float v[128];
    int k = blockIdx.x;
    int t = threadIdx.x;
    int il = t >> 4, seg = t & 15;
    int i = blockIdx.y * 16 + il;
    const float* kr = kern_l + (size_t)(k * 128 + i) * 128 + seg * 8;
    float4 ka = *(const float4*)kr;        // issue early: cold HBM
    float4 kb = *(const float4*)(kr + 4);
    // zero this block's slice of PTc: 160 blocks x 1024 floats = 64 copies x 2560
    {
        float4 z = { 0.f, 0.f, 0.f, 0.f };
        int s = k * 8 + blockIdx.y;
        *(float4*)&ptz[(size_t)s * 1024 + t * 4] = z;
    }
    if (t < 128) {
        const float* gr = Gi + k * 20;
        float s = 0.f;
#pragma unroll
        for (int m = 0; m < 20; m++) s += gr[m] * PT[m * 128 + t];
        v[t] = s;
    }
    __syncthreads();
    const float* vk = v + seg * 8;
    float4 va = *(const float4*)vk;
    float4 vb = *(const float4*)(vk + 4);
    float acc = ka.x * va.x + ka.y * va.y + ka.z * va.z + ka.w * va.w
              + kb.x * vb.x + kb.y * vb.y + kb.z * vb.z + kb.w * vb.w;
    acc += __shfl_xor(acc, 8);
    acc += __shfl_xor(acc, 4);
    acc += __shfl_xor(acc, 2);
    acc += __shfl_xor(acc, 1);
    if (seg == 0) {
        unsigned hb = rnbf(acc);
        float fh = asf(hb << 16);
        unsigned lb = rnbf(acc - fh);
        RVh[i * 32 + k] = (unsigned short)hb;
        RVl[i * 32 + k] = (unsigned short)lb;
    }
}

// ---- MFMA update: 64-row tile, 512 threads, 4 blocks/CU (160 KiB LDS).
// SPLIT-PLANE LDS: h and phi tiles as separate hi/lo ushort planes (direct b128 reads).
// Each wave owns one 32x32 output quadrant: rows (w>>2)*32, cols (w&3)*32.
// h = elu(h@W^T + phi@RV).
// l<3: re-stash, then waves 0-3 compute FULL-K PT directly + atomics (no combine
//      barriers; waves 4-7 retire early). Same 2560 atomics/block as before.
// l=3 (outp): re-stash + fused MFMA lower epilogue, skip h store.
__global__ __launch_bounds__(512, 8) void update_k(unsigned* __restrict__ hpk,
                                                   const float* __restrict__ phi,
                                                   const unsigned short* __restrict__ Wh,
                                                   const unsigned short* __restrict__ Wl,
                                                   const unsigned short* __restrict__ RVh,
                                                   const unsigned short* __restrict__ RVl,
                                                   float* __restrict__ ptn,
                                                   const unsigned short* __restrict__ LWh,
                                                   const unsigned short* __restrict__ LWl,
                                                   const float* __restrict__ low_b,
                                                   float* __restrict__ outp) {
    // 16384*2 + 4096*2 = 40960 B
    __shared__ __align__(16) unsigned short Ash[64 * 128];
    __shared__ __align__(16) unsigned short Asl[64 * 128];
    __shared__ __align__(16) unsigned short Phh[64 * 32];
    __shared__ __align__(16) unsigned short Phl[64 * 32];
    int t = threadIdx.x;
    int n0 = blockIdx.x * 64;
    // ---- stage packed h -> split planes (swizzled), packed phi -> split planes
    for (int idx = t; idx < 2048; idx += 512) {
        int row = idx >> 5, g = idx & 31;          // g: dword group of 4 cols
        uint4 v = *(const uint4*)(hpk + (size_t)(n0 + row) * 128 + g * 4);
        uint2 hv, lv;
        hv.x = __builtin_amdgcn_perm(v.y, v.x, 0x05040100u);
        hv.y = __builtin_amdgcn_perm(v.w, v.z, 0x05040100u);
        lv.x = __builtin_amdgcn_perm(v.y, v.x, 0x07060302u);
        lv.y = __builtin_amdgcn_perm(v.w, v.z, 0x07060302u);
        int base = row * 128 + (((g >> 1) ^ (row & 7)) << 3) + (g & 1) * 4;
        *(uint2*)&Ash[base] = hv;
        *(uint2*)&Asl[base] = lv;
    }
    for (int idx = t; idx < 2048; idx += 512) {
        int row = idx >> 5, kk = idx & 31;
        float pv = (kk < 20) ? phi[(size_t)(n0 + row) * 20 + kk] : 0.f;
        unsigned hb = rnbf(pv);
        float fh = asf(hb << 16);
        unsigned lb = rnbf(pv - fh);
        int pi = row * 32 + (((kk >> 3) ^ (row & 3)) << 3) + (kk & 7);
        Phh[pi] = (unsigned short)hb;
        Phl[pi] = (unsigned short)lb;
    }
    __syncthreads();

    int lane = t & 63, w = t >> 6;
    int ln = lane & 31, hw = lane >> 5;
    int r0 = (w >> 2) * 32, ct0 = (w & 3) * 32;
    int arow = r0 + ln;

    floatx16 acc;
#pragma unroll
    for (int i = 0; i < 16; i++) acc[i] = 0.f;

    const unsigned short* whp = Wh + (size_t)(ct0 + ln) * 128 + 8 * hw;
    const unsigned short* wlp = Wl + (size_t)(ct0 + ln) * 128 + 8 * hw;
    const unsigned short* ahb = Ash + arow * 128;
    const unsigned short* alb = Asl + arow * 128;
    int r7 = arow & 7;

    // ---- main K-loop (8 steps of 16): A-frags are direct b128 reads, zero perms
#pragma unroll
    for (int ks = 0; ks < 8; ks++) {
        int k0 = ks * 16;
        int gh = ((2 * ks + hw) ^ r7) << 3;
        short8 a_hi = __builtin_bit_cast(short8, *(const uint4*)(ahb + gh));
        short8 a_lo = __builtin_bit_cast(short8, *(const uint4*)(alb + gh));
        short8 bh = __builtin_bit_cast(short8, *(const uint4*)(whp + k0));
        short8 bl = __builtin_bit_cast(short8, *(const uint4*)(wlp + k0));
        acc = __builtin_amdgcn_mfma_f32_32x32x16_bf16(a_hi, bh, acc, 0, 0, 0);
        acc = __builtin_amdgcn_mfma_f32_32x32x16_bf16(a_lo, bh, acc, 0, 0, 0);
        acc = __builtin_amdgcn_mfma_f32_32x32x16_bf16(a_hi, bl, acc, 0, 0, 0);
    }

    // ---- phi @ RV: 2 more k-steps, direct b128 reads from phi planes
    const unsigned short* phb = Phh + arow * 32;
    const unsigned short* plb = Phl + arow * 32;
    int r3 = arow & 3;
#pragma unroll
    for (int ks = 0; ks < 2; ks++) {
        int k0 = ks * 16;
        int gp = ((2 * ks + hw) ^ r3) << 3;
        short8 a_hi = __builtin_bit_cast(short8, *(const uint4*)(phb + gp));
        short8 a_lo = __builtin_bit_cast(short8, *(const uint4*)(plb + gp));
        short8 bh = __builtin_bit_cast(short8, *(const uint4*)(RVh + (size_t)(ct0 + ln) * 32 + k0 + 8 * hw));
        short8 bl = __builtin_bit_cast(short8, *(const uint4*)(RVl + (size_t)(ct0 + ln) * 32 + k0 + 8 * hw));
        acc = __builtin_amdgcn_mfma_f32_32x32x16_bf16(a_hi, bh, acc, 0, 0, 0);
        acc = __builtin_amdgcn_mfma_f32_32x32x16_bf16(a_lo, bh, acc, 0, 0, 0);
        acc = __builtin_amdgcn_mfma_f32_32x32x16_bf16(a_hi, bl, acc, 0, 0, 0);
    }

    // ---- elu + pack; persist h unless this is the fused-output layer
    unsigned p0[16];
#pragma unroll
    for (int r = 0; r < 16; r++) {
        float v0 = acc[r];
        v0 = v0 > 0.f ? v0 : __expf(v0) - 1.f;
        p0[r] = packf(v0);
    }
    if (!outp) {
#pragma unroll
        for (int r = 0; r < 16; r++) {
            int row = (r & 3) + 8 * (r >> 2) + 4 * hw;
            hpk[(size_t)(n0 + r0 + row) * 128 + ct0 + ln] = p0[r];
        }
    }
    if (ptn || outp) {
        __syncthreads();   // all old-h LDS reads done
        // re-stash new h into the split planes (swizzled scalar u16 writes)
#pragma unroll
        for (int r = 0; r < 16; r++) {
            int row = r0 + (r & 3) + 8 * (r >> 2) + 4 * hw;
            int c0 = ct0 + ln;
            int si = row * 128 + (((c0 >> 3) ^ (row & 7)) << 3) + (c0 & 7);
            Ash[si] = (unsigned short)p0[r];
            Asl[si] = (unsigned short)(p0[r] >> 16);
        }
        __syncthreads();
        if (outp) {
            // MFMA lower: out = h @ lower_w^T + b. Waves 0-3 only:
            // r0o=(w>>1)*32 rows, kh=(w&1) k-half. B rows (outputs) 0-3, rows >=4 zero.
            float* scr = (float*)Phh;   // 1 KB scratch (phi planes dead at l=3)
            int r0o = (w >> 1) * 32, kh = w & 1;
            int arow2 = r0o + ln;
            const unsigned short* ah2 = Ash + arow2 * 128;
            const unsigned short* al2 = Asl + arow2 * 128;
            int rr7 = arow2 & 7;
            floatx16 ap;
#pragma unroll
            for (int i = 0; i < 16; i++) ap[i] = 0.f;
            if (w < 4) {
#pragma unroll
                for (int kk = 0; kk < 4; kk++) {
                    int ks = kh * 4 + kk;
                    int gh = ((2 * ks + hw) ^ rr7) << 3;
                    short8 a_hi = __builtin_bit_cast(short8, *(const uint4*)(ah2 + gh));
                    short8 a_lo = __builtin_bit_cast(short8, *(const uint4*)(al2 + gh));
                    short8 bh = { 0, 0, 0, 0, 0, 0, 0, 0 };
                    short8 bl = { 0, 0, 0, 0, 0, 0, 0, 0 };
                    if (ln < 4) {
                        bh = __builtin_bit_cast(short8, *(const uint4*)(LWh + ln * 128 + ks * 16 + 8 * hw));
                        bl = __builtin_bit_cast(short8, *(const uint4*)(LWl + ln * 128 + ks * 16 + 8 * hw));
                    }
                    ap = __builtin_amdgcn_mfma_f32_32x32x16_bf16(a_hi, bh, ap, 0, 0, 0);
                    ap = __builtin_amdgcn_mfma_f32_32x32x16_bf16(a_lo, bh, ap, 0, 0, 0);
                    ap = __builtin_amdgcn_mfma_f32_32x32x16_bf16(a_hi, bl, ap, 0, 0, 0);
                }
            }
            if (w < 4 && kh == 1 && ln < 4) {
#pragma unroll
                for (int r = 0; r < 16; r++) {
                    int row = (r & 3) + 8 * (r >> 2) + 4 * hw;
                    scr[(w >> 1) * 128 + row * 4 + ln] = ap[r];
                }
            }
            __syncthreads();
            if (w < 4 && kh == 0 && ln < 4) {
                float b = low_b[ln];
#pragma unroll
                for (int r = 0; r < 16; r++) {
                    int row = (r & 3) + 8 * (r >> 2) + 4 * hw;
                    float s = ap[r] + scr[(w >> 1) * 128 + row * 4 + ln] + b;
                    outp[(size_t)(n0 + r0o + row) * 4 + ln] = s;
                }
            }
        } else if (w < 4) {
            // ---- PT partial: waves 0-3 FULL-K (ks 0..3), direct atomics.
            // Exact round-3/6 gather math with the node-half split removed.
            int j0 = w * 32;
            floatx16 ap;
#pragma unroll
            for (int i = 0; i < 16; i++) ap[i] = 0.f;
#pragma unroll
            for (int ks = 0; ks < 4; ks++) {
                unsigned short ah[8], al[8], bh[8], bl[8];
#pragma unroll
                for (int j = 0; j < 8; j++) {
                    int node = ks * 16 + 8 * hw + j;
                    int pi = node * 32 + (((ln >> 3) ^ (node & 3)) << 3) + (ln & 7);
                    ah[j] = Phh[pi]; al[j] = Phl[pi];
                    int col = j0 + ln;
                    int si = node * 128 + (((col >> 3) ^ (node & 7)) << 3) + (col & 7);
                    bh[j] = Ash[si]; bl[j] = Asl[si];
                }
                uint4 qa, qb, qc, qd;
                qa.x = (unsigned)ah[0] | ((unsigned)ah[1] << 16);
                qa.y = (unsigned)ah[2] | ((unsigned)ah[3] << 16);
                qa.z = (unsigned)ah[4] | ((unsigned)ah[5] << 16);
                qa.w = (unsigned)ah[6] | ((unsigned)ah[7] << 16);
                qb.x = (unsigned)al[0] | ((unsigned)al[1] << 16);
                qb.y = (unsigned)al[2] | ((unsigned)al[3] << 16);
                qb.z = (unsigned)al[4] | ((unsigned)al[5] << 16);
                qb.w = (unsigned)al[6] | ((unsigned)al[7] << 16);
                qc.x = (unsigned)bh[0] | ((unsigned)bh[1] << 16);
                qc.y = (unsigned)bh[2] | ((unsigned)bh[3] << 16);
                qc.z = (unsigned)bh[4] | ((unsigned)bh[5] << 16);
                qc.w = (unsigned)bh[6] | ((unsigned)bh[7] << 16);
                qd.x = (unsigned)bl[0] | ((unsigned)bl[1] << 16);
                qd.y = (unsigned)bl[2] | ((unsigned)bl[3] << 16);
                qd.z = (unsigned)bl[4] | ((unsigned)bl[5] << 16);
                qd.w = (unsigned)bl[6] | ((unsigned)bl[7] << 16);
                short8 a_hi = __builtin_bit_cast(short8, qa);
                short8 a_lo = __builtin_bit_cast(short8, qb);
                short8 b_hi = __builtin_bit_cast(short8, qc);
                short8 b_lo = __builtin_bit_cast(short8, qd);
                ap = __builtin_amdgcn_mfma_f32_32x32x16_bf16(a_hi, b_hi, ap, 0, 0, 0);
                ap = __builtin_amdgcn_mfma_f32_32x32x16_bf16(a_lo, b_hi, ap, 0, 0, 0);
                ap = __builtin_amdgcn_mfma_f32_32x32x16_bf16(a_hi, b_lo, ap, 0, 0, 0);
            }
            float* blk = ptn + (size_t)(blockIdx.x & 63) * 2560;
#pragma unroll
            for (int r = 0; r < 16; r++) {
                int mode = (r & 3) + 8 * (r >> 2) + 4 * hw;
                if (mode < 20) unsafeAtomicAdd(&blk[mode * 128 + j0 + ln], ap[r]);
            }
        }
    }
}

extern "C" void kernel_launch(void* const* d_in, const int* in_sizes, int n_in,
                              void* d_out, int out_size, void* d_ws, size_t ws_size,
                              hipStream_t stream) {
    (void)in_sizes; (void)n_in; (void)out_size; (void)ws_size;
    const float* x       = (const float*)d_in[0];
    const float* pos     = (const float*)d_in[1];
    const float* y       = (const float*)d_in[2];
    const float* phi     = (const float*)d_in[3];
    const float* lift_w  = (const float*)d_in[4];
    const float* lift_b  = (const float*)d_in[5];
    const float* lin_w   = (const float*)d_in[6];
    const float* kern    = (const float*)d_in[7];
    const float* lower_w = (const float*)d_in[8];
    const float* lower_b = (const float*)d_in[9];
    float* out = (float*)d_out;

    char* ws = (char*)d_ws;
    unsigned* hpk = (unsigned*)ws;                       // 102,400,000 B
    size_t off = (size_t)Nn * 128 * 4;
    float* b2  = (float*)(ws + off);       off += 512;    // unused, layout kept
    float* G   = (float*)(ws + off);       off += 1600;
    float* Gi  = (float*)(ws + off);       off += 1600;
    off = (off + 15) & ~(size_t)15;
    float* PT  = (float*)(ws + off);       off += 10240;
    float* PTc = (float*)(ws + off);       off += 64 * 2560 * 4;   // 640 KB
    unsigned short* W_hi = (unsigned short*)(ws + off);  off += 131072;
    unsigned short* W_lo = (unsigned short*)(ws + off);  off += 131072;
    unsigned short* RVh  = (unsigned short*)(ws + off);  off += 8192;
    unsigned short* RVl  = (unsigned short*)(ws + off);  off += 8192;
    unsigned short* LWh  = (unsigned short*)(ws + off);  off += 1024;
    unsigned short* LWl  = (unsigned short*)(ws + off);  off += 1024;
    (void)b2;

    hipMemsetAsync(G, 0, 1600, stream);
    hipMemsetAsync(PTc, 0, 64 * 2560 * 4, stream);
    hipMemsetAsync(RVh, 0, 16384, stream);   // RVh+RVl adjacent
    wsplit_k<<<258, 256, 0, stream>>>(lin_w, lower_w, W_hi, W_lo, LWh, LWl);
    lift_k<<<NT, 512, 0, stream>>>(x, pos, phi, lift_w, lift_b, y, hpk, PTc);
    gram_k<<<256, 256, 0, stream>>>(phi, G);
    ginv_k<<<1, 64, 0, stream>>>(G, Gi);
    ptreduce_k<<<20, 128, 0, stream>>>(PTc, PT);

    for (int l = 0; l < 4; l++) {
        // rv also zeroes PTc for the coming update (ptreduce for prev layer is done)
        rv_k<<<dim3(20, 8), 256, 0, stream>>>(Gi, PT, kern + (size_t)l * 20 * 128 * 128,
                                              RVh, RVl, PTc);
        float* ptc = (l < 3) ? PTc : (float*)nullptr;
        update_k<<<NT, 512, 0, stream>>>(hpk, phi, W_hi + (size_t)l * 16384,
                                         W_lo + (size_t)l * 16384, RVh, RVl, ptc,
                                         LWh, LWl, lower_b,
                                         (l == 3) ? out : (float*)nullptr);
        if (ptc) ptreduce_k<<<20, 128, 0, stream>>>(PTc, PT);
    }
}

// Round 12
// 582.371 us; speedup vs baseline: 1.1452x; 1.0096x over previous
//
#include <hip/hip_runtime.h>
#include <math.h>

#define Nn 200000
#define NT 3125   // Nn / 64

typedef __attribute__((ext_vector_type(8))) short short8;
typedef __attribute__((ext_vector_type(16))) float floatx16;

// XOR swizzle for packed (dword) tiles: column-group g (4 dwords) XOR'd with (row & 7).
#define SWZ4(row, g) (((g) ^ ((row) & 7)) << 2)

// ---- bf16 split helpers (RNE) ----
__device__ __forceinline__ unsigned rnbf(float x) {
    unsigned u = __builtin_bit_cast(unsigned, x);
    return (u + 0x7fffu + ((u >> 16) & 1u)) >> 16;
}
__device__ __forceinline__ float asf(unsigned u) { return __builtin_bit_cast(float, u); }
// packed element: low16 = hi bf16, high16 = lo bf16
__device__ __forceinline__ unsigned packf(float x) {
    unsigned hb = rnbf(x);
    float fh = asf(hb << 16);
    unsigned lb = rnbf(x - fh);
    return hb | (lb << 16);
}
__device__ __forceinline__ void permsplit(const unsigned* e, short8& hi, short8& lo) {
    uint4 h, l;
    h.x = __builtin_amdgcn_perm(e[1], e[0], 0x05040100u);
    h.y = __builtin_amdgcn_perm(e[3], e[2], 0x05040100u);
    h.z = __builtin_amdgcn_perm(e[5], e[4], 0x05040100u);
    h.w = __builtin_amdgcn_perm(e[7], e[6], 0x05040100u);
    l.x = __builtin_amdgcn_perm(e[1], e[0], 0x07060302u);
    l.y = __builtin_amdgcn_perm(e[3], e[2], 0x07060302u);
    l.z = __builtin_amdgcn_perm(e[5], e[4], 0x07060302u);
    l.w = __builtin_amdgcn_perm(e[7], e[6], 0x07060302u);
    hi = __builtin_bit_cast(short8, h);
    lo = __builtin_bit_cast(short8, l);
}

// ---- 8-wave PT partial MFMA over packed swizzled tiles (round-3 verified):
// wave (w&3) -> col block, (w>>2) -> node half (K=32 each). Used by lift_k.
__device__ __forceinline__ void pt_mfma8(const unsigned* As, const unsigned* Ph,
                                         floatx16& ap, int t) {
    int lane = t & 63, w = t >> 6;
    int ln = lane & 31, hw = lane >> 5;
    int j0 = (w & 3) * 32;
    int nh = w >> 2;
#pragma unroll
    for (int i = 0; i < 16; i++) ap[i] = 0.f;
#pragma unroll
    for (int ks2 = 0; ks2 < 2; ks2++) {
        int ks = nh * 2 + ks2;
        unsigned pa[8], e[8];
#pragma unroll
        for (int j = 0; j < 8; j++) {
            int node = ks * 16 + 8 * hw + j;
            pa[j] = Ph[node * 32 + SWZ4(node, ln >> 2) + (ln & 3)];
            int col = j0 + ln;
            e[j] = As[node * 128 + SWZ4(node, col >> 2) + (col & 3)];
        }
        short8 a_hi, a_lo, b_hi, b_lo;
        permsplit(pa, a_hi, a_lo);
        permsplit(e, b_hi, b_lo);
        ap = __builtin_amdgcn_mfma_f32_32x32x16_bf16(a_hi, b_hi, ap, 0, 0, 0);
        ap = __builtin_amdgcn_mfma_f32_32x32x16_bf16(a_lo, b_hi, ap, 0, 0, 0);
        ap = __builtin_amdgcn_mfma_f32_32x32x16_bf16(a_hi, b_lo, ap, 0, 0, 0);
    }
}

// ---- PT reduce, wave-per-element: block j (0..2559), 64 lanes = 64 copies.
// One load per lane (640 KB L2-resident), 6-step shuffle reduce, lane-0 store.
__global__ void ptreduce_k(const float* __restrict__ PTc, float* __restrict__ PT) {
    int j = blockIdx.x;
    int c = threadIdx.x;
    float s = PTc[(size_t)c * 2560 + j];
    s += __shfl_xor(s, 32);
    s += __shfl_xor(s, 16);
    s += __shfl_xor(s, 8);
    s += __shfl_xor(s, 4);
    s += __shfl_xor(s, 2);
    s += __shfl_xor(s, 1);
    if (c == 0) PT[j] = s;
}

// ---- split lin_w (65536) + lower_w (512) into bf16 hi/lo. grid 258 x 256.
__global__ void wsplit_k(const float* __restrict__ lw, const float* __restrict__ low_w,
                         unsigned short* __restrict__ Wh, unsigned short* __restrict__ Wl,
                         unsigned short* __restrict__ LWh, unsigned short* __restrict__ LWl) {
    int i = blockIdx.x * 256 + threadIdx.x;
    float w;
    unsigned short *ph, *pl;
    int idx;
    if (i < 65536) { w = lw[i]; ph = Wh; pl = Wl; idx = i; }
    else           { w = low_w[i - 65536]; ph = LWh; pl = LWl; idx = i - 65536; }
    unsigned hb = rnbf(w);
    float fh = asf(hb << 16);
    unsigned lb = rnbf(w - fh);
    ph[idx] = (unsigned short)hb;
    pl[idx] = (unsigned short)lb;
}

// ---- lift (GEMM tile) + inline y-bias fold + fused PT0 partial.
// 512 threads (8 waves), 4 blocks/CU (160 KiB LDS) -> 32 waves/CU occupancy cap.
// PT tail: 8-wave pt_mfma8 + LDS combine of node halves -> 2560 atomics/block.
__global__ __launch_bounds__(512, 8) void lift_k(const float* __restrict__ x,
                                                 const float* __restrict__ pos,
                                                 const float* __restrict__ phi,
                                                 const float* __restrict__ lw,
                                                 const float* __restrict__ lb,
                                                 const float* __restrict__ yg,
                                                 unsigned* __restrict__ hpk,
                                                 float* __restrict__ PTc) {
    __shared__ union {
        struct { float xs[64][21]; float Wc[20][132]; } a;
        unsigned As[64 * 128];
    } sm;
    __shared__ unsigned Ph[64 * 32];
    int t = threadIdx.x;
    int n0 = blockIdx.x * 64;
    if (t < 256) {
        int n = t >> 2, f4 = (t & 3) * 4;
        float4 xv = *(const float4*)(x + (size_t)(n0 + n) * 16 + f4);
        sm.a.xs[n][f4 + 0] = xv.x; sm.a.xs[n][f4 + 1] = xv.y;
        sm.a.xs[n][f4 + 2] = xv.z; sm.a.xs[n][f4 + 3] = xv.w;
    }
    if (t < 192) { int n = t / 3, d = t % 3; sm.a.xs[n][16 + d] = pos[(size_t)(n0 + n) * 3 + d]; }
    if (t < 64) sm.a.xs[t][19] = 1.f;
    for (int idx = t; idx < 2560; idx += 512) {
        int k = idx >> 7, j = idx & 127;
        float wv;
        if (k < 19) {
            wv = lw[j * 22 + k];
        } else {
            wv = lb[j] + yg[0] * lw[j * 22 + 19] + yg[1] * lw[j * 22 + 20]
                       + yg[2] * lw[j * 22 + 21];
        }
        sm.a.Wc[k][j] = wv;
    }
    for (int idx = t; idx < 2048; idx += 512) {
        int row = idx >> 5, kk = idx & 31;
        float pv = (kk < 20) ? phi[(size_t)(n0 + row) * 20 + kk] : 0.f;
        Ph[row * 32 + SWZ4(row, kk >> 2) + (kk & 3)] = packf(pv);
    }
    __syncthreads();
    // GEMM: 512 threads, each 4 rows (ty + 16*m) x 4 cols (tx*4..+3)
    int tx = t & 31, ty = t >> 5, i0 = tx * 4;
    float acc[4][4];
#pragma unroll
    for (int m = 0; m < 4; m++)
#pragma unroll
        for (int c = 0; c < 4; c++) acc[m][c] = 0.f;
#pragma unroll 4
    for (int k = 0; k < 20; k++) {
        float4 w = *(const float4*)&sm.a.Wc[k][i0];
#pragma unroll
        for (int m = 0; m < 4; m++) {
            float a = sm.a.xs[ty + 16 * m][k];
            acc[m][0] += a * w.x; acc[m][1] += a * w.y;
            acc[m][2] += a * w.z; acc[m][3] += a * w.w;
        }
    }
    __syncthreads();   // xs/Wc reads done before As overwrites the union
#pragma unroll
    for (int m = 0; m < 4; m++) {
        uint4 o;
        o.x = packf(acc[m][0]); o.y = packf(acc[m][1]);
        o.z = packf(acc[m][2]); o.w = packf(acc[m][3]);
        int row = ty + 16 * m;
        *(uint4*)&hpk[(size_t)(n0 + row) * 128 + i0] = o;
        *(uint4*)&sm.As[row * 128 + SWZ4(row, tx)] = o;
    }
    __syncthreads();
    floatx16 ap;
    pt_mfma8(sm.As, Ph, ap, t);
    int lane = t & 63, w = t >> 6;
    int ln = lane & 31, hw = lane >> 5;
    int j0 = (w & 3) * 32, nh = w >> 2;
    __syncthreads();            // all As/Ph reads done before overlay
    float* PTs = (float*)sm.As; // 10 KB scratch overlay (As dead now)
    if (nh == 1) {
#pragma unroll
        for (int r = 0; r < 16; r++) {
            int mode = (r & 3) + 8 * (r >> 2) + 4 * hw;
            if (mode < 20) PTs[mode * 128 + j0 + ln] = ap[r];
        }
    }
    __syncthreads();
    if (nh == 0) {
        float* blk = PTc + (size_t)(blockIdx.x & 63) * 2560;
#pragma unroll
        for (int r = 0; r < 16; r++) {
            int mode = (r & 3) + 8 * (r >> 2) + 4 * hw;
            if (mode < 20) {
                int idx = mode * 128 + j0 + ln;
                unsafeAtomicAdd(&blk[idx], ap[r] + PTs[idx]);
            }
        }
    }
}

// ---- G = phi^T phi  (20x20)
__global__ void gram_k(const float* __restrict__ phi, float* __restrict__ G) {
    __shared__ float ph[64 * 20];
    int t = threadIdx.x;
    int i0 = t / 20, j0 = t % 20;
    int p1 = t + 256;
    int i1 = p1 / 20, j1 = p1 % 20;
    float a0 = 0.f, a1 = 0.f;
    for (int tile = blockIdx.x; tile < NT; tile += gridDim.x) {
        const float* src = phi + tile * 1280;
        for (int idx = t; idx < 1280; idx += 256) ph[idx] = src[idx];
        __syncthreads();
        for (int n = 0; n < 64; n++) {
            const float* r = ph + n * 20;
            a0 += r[i0] * r[j0];
            if (p1 < 400) a1 += r[i1] * r[j1];
        }
        __syncthreads();
    }
    unsafeAtomicAdd(&G[t], a0);
    if (p1 < 400) unsafeAtomicAdd(&G[p1], a1);
}

// ---- Gauss-Jordan inverse of 20x20
__global__ void ginv_k(const float* __restrict__ G, float* __restrict__ Gi) {
    __shared__ float A[20][40];
    __shared__ float colp[20];
    __shared__ float piv;
    int t = threadIdx.x;
    for (int idx = t; idx < 400; idx += 64) {
        int r = idx / 20, c = idx % 20;
        A[r][c] = G[idx];
        A[r][c + 20] = (r == c) ? 1.f : 0.f;
    }
    __syncthreads();
    for (int p = 0; p < 20; p++) {
        if (t == 0) piv = 1.f / A[p][p];
        __syncthreads();
        for (int c = t; c < 40; c += 64) A[p][c] *= piv;
        __syncthreads();
        if (t < 20) colp[t] = A[t][p];
        __syncthreads();
        for (int e = t; e < 800; e += 64) {
            int r = e / 40, c = e % 40;
            if (r != p) A[r][c] -= colp[r] * A[p][c];
        }
        __syncthreads();
    }
    for (int idx = t; idx < 400; idx += 64) {
        int r = idx / 20, c = idx % 20;
        Gi[idx] = A[r][c + 20];
    }
}

// ---- v[k] = Gi[k] @ PT; RV = kernel[l][k] @ v[k]. Widened: grid (20, 8) x 256.
// kern loads hoisted ABOVE the zero/v phase so cold-HBM latency hides under it.
// Also zeros its 4 KB slice of PTc (replaces the per-layer memset dispatch).
__global__ void rv_k(const float* __restrict__ Gi, const float* __restrict__ PT,
                     const float* __restrict__ kern_l,
                     unsigned short* __restrict__ RVh, unsigned short* __restrict__ RVl,
                     float* __restrict__ ptz) {
    __shared__ __align__(16) float v[128];
    int k = blockIdx.x;
    int t = threadIdx.x;
    int il = t >> 4, seg = t & 15;
    int i = blockIdx.y * 16 + il;
    const float* kr = kern_l + (size_t)(k * 128 + i) * 128 + seg * 8;
    float4 ka = *(const float4*)kr;        // issue early: cold HBM
    float4 kb = *(const float4*)(kr + 4);
    // zero this block's slice of PTc: 160 blocks x 1024 floats = 64 copies x 2560
    {
        float4 z = { 0.f, 0.f, 0.f, 0.f };
        int s = k * 8 + blockIdx.y;
        *(float4*)&ptz[(size_t)s * 1024 + t * 4] = z;
    }
    if (t < 128) {
        const float* gr = Gi + k * 20;
        float s = 0.f;
#pragma unroll
        for (int m = 0; m < 20; m++) s += gr[m] * PT[m * 128 + t];
        v[t] = s;
    }
    __syncthreads();
    const float* vk = v + seg * 8;
    float4 va = *(const float4*)vk;
    float4 vb = *(const float4*)(vk + 4);
    float acc = ka.x * va.x + ka.y * va.y + ka.z * va.z + ka.w * va.w
              + kb.x * vb.x + kb.y * vb.y + kb.z * vb.z + kb.w * vb.w;
    acc += __shfl_xor(acc, 8);
    acc += __shfl_xor(acc, 4);
    acc += __shfl_xor(acc, 2);
    acc += __shfl_xor(acc, 1);
    if (seg == 0) {
        unsigned hb = rnbf(acc);
        float fh = asf(hb << 16);
        unsigned lb = rnbf(acc - fh);
        RVh[i * 32 + k] = (unsigned short)hb;
        RVl[i * 32 + k] = (unsigned short)lb;
    }
}

// ---- MFMA update: 64-row tile, 512 threads, 4 blocks/CU (160 KiB LDS).
// SPLIT-PLANE LDS: h and phi tiles as separate hi/lo ushort planes (direct b128 reads).
// Each wave owns one 32x32 output quadrant: rows (w>>2)*32, cols (w&3)*32.
// h = elu(h@W^T + phi@RV).
// l<3: re-stash, then waves 0-3 compute FULL-K PT directly + atomics (no combine
//      barriers; waves 4-7 retire early). Same 2560 atomics/block as before.
// l=3 (outp): re-stash + fused MFMA lower epilogue, skip h store.
__global__ __launch_bounds__(512, 8) void update_k(unsigned* __restrict__ hpk,
                                                   const float* __restrict__ phi,
                                                   const unsigned short* __restrict__ Wh,
                                                   const unsigned short* __restrict__ Wl,
                                                   const unsigned short* __restrict__ RVh,
                                                   const unsigned short* __restrict__ RVl,
                                                   float* __restrict__ ptn,
                                                   const unsigned short* __restrict__ LWh,
                                                   const unsigned short* __restrict__ LWl,
                                                   const float* __restrict__ low_b,
                                                   float* __restrict__ outp) {
    // 16384*2 + 4096*2 = 40960 B
    __shared__ __align__(16) unsigned short Ash[64 * 128];
    __shared__ __align__(16) unsigned short Asl[64 * 128];
    __shared__ __align__(16) unsigned short Phh[64 * 32];
    __shared__ __align__(16) unsigned short Phl[64 * 32];
    int t = threadIdx.x;
    int n0 = blockIdx.x * 64;
    // ---- stage packed h -> split planes (swizzled), packed phi -> split planes
    for (int idx = t; idx < 2048; idx += 512) {
        int row = idx >> 5, g = idx & 31;          // g: dword group of 4 cols
        uint4 v = *(const uint4*)(hpk + (size_t)(n0 + row) * 128 + g * 4);
        uint2 hv, lv;
        hv.x = __builtin_amdgcn_perm(v.y, v.x, 0x05040100u);
        hv.y = __builtin_amdgcn_perm(v.w, v.z, 0x05040100u);
        lv.x = __builtin_amdgcn_perm(v.y, v.x, 0x07060302u);
        lv.y = __builtin_amdgcn_perm(v.w, v.z, 0x07060302u);
        int base = row * 128 + (((g >> 1) ^ (row & 7)) << 3) + (g & 1) * 4;
        *(uint2*)&Ash[base] = hv;
        *(uint2*)&Asl[base] = lv;
    }
    for (int idx = t; idx < 2048; idx += 512) {
        int row = idx >> 5, kk = idx & 31;
        float pv = (kk < 20) ? phi[(size_t)(n0 + row) * 20 + kk] : 0.f;
        unsigned hb = rnbf(pv);
        float fh = asf(hb << 16);
        unsigned lb = rnbf(pv - fh);
        int pi = row * 32 + (((kk >> 3) ^ (row & 3)) << 3) + (kk & 7);
        Phh[pi] = (unsigned short)hb;
        Phl[pi] = (unsigned short)lb;
    }
    __syncthreads();

    int lane = t & 63, w = t >> 6;
    int ln = lane & 31, hw = lane >> 5;
    int r0 = (w >> 2) * 32, ct0 = (w & 3) * 32;
    int arow = r0 + ln;

    floatx16 acc;
#pragma unroll
    for (int i = 0; i < 16; i++) acc[i] = 0.f;

    const unsigned short* whp = Wh + (size_t)(ct0 + ln) * 128 + 8 * hw;
    const unsigned short* wlp = Wl + (size_t)(ct0 + ln) * 128 + 8 * hw;
    const unsigned short* ahb = Ash + arow * 128;
    const unsigned short* alb = Asl + arow * 128;
    int r7 = arow & 7;

    // ---- main K-loop (8 steps of 16): A-frags are direct b128 reads, zero perms
#pragma unroll
    for (int ks = 0; ks < 8; ks++) {
        int k0 = ks * 16;
        int gh = ((2 * ks + hw) ^ r7) << 3;
        short8 a_hi = __builtin_bit_cast(short8, *(const uint4*)(ahb + gh));
        short8 a_lo = __builtin_bit_cast(short8, *(const uint4*)(alb + gh));
        short8 bh = __builtin_bit_cast(short8, *(const uint4*)(whp + k0));
        short8 bl = __builtin_bit_cast(short8, *(const uint4*)(wlp + k0));
        acc = __builtin_amdgcn_mfma_f32_32x32x16_bf16(a_hi, bh, acc, 0, 0, 0);
        acc = __builtin_amdgcn_mfma_f32_32x32x16_bf16(a_lo, bh, acc, 0, 0, 0);
        acc = __builtin_amdgcn_mfma_f32_32x32x16_bf16(a_hi, bl, acc, 0, 0, 0);
    }

    // ---- phi @ RV: 2 more k-steps, direct b128 reads from phi planes
    const unsigned short* phb = Phh + arow * 32;
    const unsigned short* plb = Phl + arow * 32;
    int r3 = arow & 3;
#pragma unroll
    for (int ks = 0; ks < 2; ks++) {
        int k0 = ks * 16;
        int gp = ((2 * ks + hw) ^ r3) << 3;
        short8 a_hi = __builtin_bit_cast(short8, *(const uint4*)(phb + gp));
        short8 a_lo = __builtin_bit_cast(short8, *(const uint4*)(plb + gp));
        short8 bh = __builtin_bit_cast(short8, *(const uint4*)(RVh + (size_t)(ct0 + ln) * 32 + k0 + 8 * hw));
        short8 bl = __builtin_bit_cast(short8, *(const uint4*)(RVl + (size_t)(ct0 + ln) * 32 + k0 + 8 * hw));
        acc = __builtin_amdgcn_mfma_f32_32x32x16_bf16(a_hi, bh, acc, 0, 0, 0);
        acc = __builtin_amdgcn_mfma_f32_32x32x16_bf16(a_lo, bh, acc, 0, 0, 0);
        acc = __builtin_amdgcn_mfma_f32_32x32x16_bf16(a_hi, bl, acc, 0, 0, 0);
    }

    // ---- elu + pack; persist h unless this is the fused-output layer
    unsigned p0[16];
#pragma unroll
    for (int r = 0; r < 16; r++) {
        float v0 = acc[r];
        v0 = v0 > 0.f ? v0 : __expf(v0) - 1.f;
        p0[r] = packf(v0);
    }
    if (!outp) {
#pragma unroll
        for (int r = 0; r < 16; r++) {
            int row = (r & 3) + 8 * (r >> 2) + 4 * hw;
            hpk[(size_t)(n0 + r0 + row) * 128 + ct0 + ln] = p0[r];
        }
    }
    if (ptn || outp) {
        __syncthreads();   // all old-h LDS reads done
        // re-stash new h into the split planes (swizzled scalar u16 writes)
#pragma unroll
        for (int r = 0; r < 16; r++) {
            int row = r0 + (r & 3) + 8 * (r >> 2) + 4 * hw;
            int c0 = ct0 + ln;
            int si = row * 128 + (((c0 >> 3) ^ (row & 7)) << 3) + (c0 & 7);
            Ash[si] = (unsigned short)p0[r];
            Asl[si] = (unsigned short)(p0[r] >> 16);
        }
        __syncthreads();
        if (outp) {
            // MFMA lower: out = h @ lower_w^T + b. Waves 0-3 only:
            // r0o=(w>>1)*32 rows, kh=(w&1) k-half. B rows (outputs) 0-3, rows >=4 zero.
            float* scr = (float*)Phh;   // 1 KB scratch (phi planes dead at l=3)
            int r0o = (w >> 1) * 32, kh = w & 1;
            int arow2 = r0o + ln;
            const unsigned short* ah2 = Ash + arow2 * 128;
            const unsigned short* al2 = Asl + arow2 * 128;
            int rr7 = arow2 & 7;
            floatx16 ap;
#pragma unroll
            for (int i = 0; i < 16; i++) ap[i] = 0.f;
            if (w < 4) {
#pragma unroll
                for (int kk = 0; kk < 4; kk++) {
                    int ks = kh * 4 + kk;
                    int gh = ((2 * ks + hw) ^ rr7) << 3;
                    short8 a_hi = __builtin_bit_cast(short8, *(const uint4*)(ah2 + gh));
                    short8 a_lo = __builtin_bit_cast(short8, *(const uint4*)(al2 + gh));
                    short8 bh = { 0, 0, 0, 0, 0, 0, 0, 0 };
                    short8 bl = { 0, 0, 0, 0, 0, 0, 0, 0 };
                    if (ln < 4) {
                        bh = __builtin_bit_cast(short8, *(const uint4*)(LWh + ln * 128 + ks * 16 + 8 * hw));
                        bl = __builtin_bit_cast(short8, *(const uint4*)(LWl + ln * 128 + ks * 16 + 8 * hw));
                    }
                    ap = __builtin_amdgcn_mfma_f32_32x32x16_bf16(a_hi, bh, ap, 0, 0, 0);
                    ap = __builtin_amdgcn_mfma_f32_32x32x16_bf16(a_lo, bh, ap, 0, 0, 0);
                    ap = __builtin_amdgcn_mfma_f32_32x32x16_bf16(a_hi, bl, ap, 0, 0, 0);
                }
            }
            if (w < 4 && kh == 1 && ln < 4) {
#pragma unroll
                for (int r = 0; r < 16; r++) {
                    int row = (r & 3) + 8 * (r >> 2) + 4 * hw;
                    scr[(w >> 1) * 128 + row * 4 + ln] = ap[r];
                }
            }
            __syncthreads();
            if (w < 4 && kh == 0 && ln < 4) {
                float b = low_b[ln];
#pragma unroll
                for (int r = 0; r < 16; r++) {
                    int row = (r & 3) + 8 * (r >> 2) + 4 * hw;
                    float s = ap[r] + scr[(w >> 1) * 128 + row * 4 + ln] + b;
                    outp[(size_t)(n0 + r0o + row) * 4 + ln] = s;
                }
            }
        } else if (w < 4) {
            // ---- PT partial: waves 0-3 FULL-K (ks 0..3), direct atomics.
            // Exact round-3/6 gather math with the node-half split removed.
            int j0 = w * 32;
            floatx16 ap;
#pragma unroll
            for (int i = 0; i < 16; i++) ap[i] = 0.f;
#pragma unroll
            for (int ks = 0; ks < 4; ks++) {
                unsigned short ah[8], al[8], bh[8], bl[8];
#pragma unroll
                for (int j = 0; j < 8; j++) {
                    int node = ks * 16 + 8 * hw + j;
                    int pi = node * 32 + (((ln >> 3) ^ (node & 3)) << 3) + (ln & 7);
                    ah[j] = Phh[pi]; al[j] = Phl[pi];
                    int col = j0 + ln;
                    int si = node * 128 + (((col >> 3) ^ (node & 7)) << 3) + (col & 7);
                    bh[j] = Ash[si]; bl[j] = Asl[si];
                }
                uint4 qa, qb, qc, qd;
                qa.x = (unsigned)ah[0] | ((unsigned)ah[1] << 16);
                qa.y = (unsigned)ah[2] | ((unsigned)ah[3] << 16);
                qa.z = (unsigned)ah[4] | ((unsigned)ah[5] << 16);
                qa.w = (unsigned)ah[6] | ((unsigned)ah[7] << 16);
                qb.x = (unsigned)al[0] | ((unsigned)al[1] << 16);
                qb.y = (unsigned)al[2] | ((unsigned)al[3] << 16);
                qb.z = (unsigned)al[4] | ((unsigned)al[5] << 16);
                qb.w = (unsigned)al[6] | ((unsigned)al[7] << 16);
                qc.x = (unsigned)bh[0] | ((unsigned)bh[1] << 16);
                qc.y = (unsigned)bh[2] | ((unsigned)bh[3] << 16);
                qc.z = (unsigned)bh[4] | ((unsigned)bh[5] << 16);
                qc.w = (unsigned)bh[6] | ((unsigned)bh[7] << 16);
                qd.x = (unsigned)bl[0] | ((unsigned)bl[1] << 16);
                qd.y = (unsigned)bl[2] | ((unsigned)bl[3] << 16);
                qd.z = (unsigned)bl[4] | ((unsigned)bl[5] << 16);
                qd.w = (unsigned)bl[6] | ((unsigned)bl[7] << 16);
                short8 a_hi = __builtin_bit_cast(short8, qa);
                short8 a_lo = __builtin_bit_cast(short8, qb);
                short8 b_hi = __builtin_bit_cast(short8, qc);
                short8 b_lo = __builtin_bit_cast(short8, qd);
                ap = __builtin_amdgcn_mfma_f32_32x32x16_bf16(a_hi, b_hi, ap, 0, 0, 0);
                ap = __builtin_amdgcn_mfma_f32_32x32x16_bf16(a_lo, b_hi, ap, 0, 0, 0);
                ap = __builtin_amdgcn_mfma_f32_32x32x16_bf16(a_hi, b_lo, ap, 0, 0, 0);
            }
            float* blk = ptn + (size_t)(blockIdx.x & 63) * 2560;
#pragma unroll
            for (int r = 0; r < 16; r++) {
                int mode = (r & 3) + 8 * (r >> 2) + 4 * hw;
                if (mode < 20) unsafeAtomicAdd(&blk[mode * 128 + j0 + ln], ap[r]);
            }
        }
    }
}

extern "C" void kernel_launch(void* const* d_in, const int* in_sizes, int n_in,
                              void* d_out, int out_size, void* d_ws, size_t ws_size,
                              hipStream_t stream) {
    (void)in_sizes; (void)n_in; (void)out_size; (void)ws_size;
    const float* x       = (const float*)d_in[0];
    const float* pos     = (const float*)d_in[1];
    const float* y       = (const float*)d_in[2];
    const float* phi     = (const float*)d_in[3];
    const float* lift_w  = (const float*)d_in[4];
    const float* lift_b  = (const float*)d_in[5];
    const float* lin_w   = (const float*)d_in[6];
    const float* kern    = (const float*)d_in[7];
    const float* lower_w = (const float*)d_in[8];
    const float* lower_b = (const float*)d_in[9];
    float* out = (float*)d_out;

    char* ws = (char*)d_ws;
    unsigned* hpk = (unsigned*)ws;                       // 102,400,000 B
    size_t off = (size_t)Nn * 128 * 4;
    float* b2  = (float*)(ws + off);       off += 512;    // unused, layout kept
    float* G   = (float*)(ws + off);       off += 1600;
    float* Gi  = (float*)(ws + off);       off += 1600;
    off = (off + 15) & ~(size_t)15;
    float* PT  = (float*)(ws + off);       off += 10240;
    float* PTc = (float*)(ws + off);       off += 64 * 2560 * 4;   // 640 KB
    unsigned short* W_hi = (unsigned short*)(ws + off);  off += 131072;
    unsigned short* W_lo = (unsigned short*)(ws + off);  off += 131072;
    unsigned short* RVh  = (unsigned short*)(ws + off);  off += 8192;
    unsigned short* RVl  = (unsigned short*)(ws + off);  off += 8192;
    unsigned short* LWh  = (unsigned short*)(ws + off);  off += 1024;
    unsigned short* LWl  = (unsigned short*)(ws + off);  off += 1024;
    (void)b2;

    hipMemsetAsync(G, 0, 1600, stream);
    hipMemsetAsync(PTc, 0, 64 * 2560 * 4, stream);
    hipMemsetAsync(RVh, 0, 16384, stream);   // RVh+RVl adjacent
    wsplit_k<<<258, 256, 0, stream>>>(lin_w, lower_w, W_hi, W_lo, LWh, LWl);
    lift_k<<<NT, 512, 0, stream>>>(x, pos, phi, lift_w, lift_b, y, hpk, PTc);
    gram_k<<<256, 256, 0, stream>>>(phi, G);
    ginv_k<<<1, 64, 0, stream>>>(G, Gi);
    ptreduce_k<<<2560, 64, 0, stream>>>(PTc, PT);

    for (int l = 0; l < 4; l++) {
        // rv also zeroes PTc for the coming update (ptreduce for prev layer is done)
        rv_k<<<dim3(20, 8), 256, 0, stream>>>(Gi, PT, kern + (size_t)l * 20 * 128 * 128,
                                              RVh, RVl, PTc);
        float* ptc = (l < 3) ? PTc : (float*)nullptr;
        update_k<<<NT, 512, 0, stream>>>(hpk, phi, W_hi + (size_t)l * 16384,
                                         W_lo + (size_t)l * 16384, RVh, RVl, ptc,
                                         LWh, LWl, lower_b,
                                         (l == 3) ? out : (float*)nullptr);
        if (ptc) ptreduce_k<<<2560, 64, 0, stream>>>(PTc, PT);
    }
}

// Round 13
// 562.445 us; speedup vs baseline: 1.1858x; 1.0354x over previous
//
#include <hip/hip_runtime.h>
#include <math.h>

#define Nn 200000
#define NT 3125   // Nn / 64

typedef __attribute__((ext_vector_type(8))) short short8;
typedef __attribute__((ext_vector_type(16))) float floatx16;

// XOR swizzle for packed (dword) tiles: column-group g (4 dwords) XOR'd with (row & 7).
#define SWZ4(row, g) (((g) ^ ((row) & 7)) << 2)

// ---- bf16 split helpers (RNE) ----
__device__ __forceinline__ unsigned rnbf(float x) {
    unsigned u = __builtin_bit_cast(unsigned, x);
    return (u + 0x7fffu + ((u >> 16) & 1u)) >> 16;
}
__device__ __forceinline__ float asf(unsigned u) { return __builtin_bit_cast(float, u); }
// packed element: low16 = hi bf16, high16 = lo bf16
__device__ __forceinline__ unsigned packf(float x) {
    unsigned hb = rnbf(x);
    float fh = asf(hb << 16);
    unsigned lb = rnbf(x - fh);
    return hb | (lb << 16);
}
__device__ __forceinline__ void permsplit(const unsigned* e, short8& hi, short8& lo) {
    uint4 h, l;
    h.x = __builtin_amdgcn_perm(e[1], e[0], 0x05040100u);
    h.y = __builtin_amdgcn_perm(e[3], e[2], 0x05040100u);
    h.z = __builtin_amdgcn_perm(e[5], e[4], 0x05040100u);
    h.w = __builtin_amdgcn_perm(e[7], e[6], 0x05040100u);
    l.x = __builtin_amdgcn_perm(e[1], e[0], 0x07060302u);
    l.y = __builtin_amdgcn_perm(e[3], e[2], 0x07060302u);
    l.z = __builtin_amdgcn_perm(e[5], e[4], 0x07060302u);
    l.w = __builtin_amdgcn_perm(e[7], e[6], 0x07060302u);
    hi = __builtin_bit_cast(short8, h);
    lo = __builtin_bit_cast(short8, l);
}

// ---- 8-wave PT partial MFMA over packed swizzled tiles (round-3 verified):
// wave (w&3) -> col block, (w>>2) -> node half (K=32 each). Used by lift_k.
__device__ __forceinline__ void pt_mfma8(const unsigned* As, const unsigned* Ph,
                                         floatx16& ap, int t) {
    int lane = t & 63, w = t >> 6;
    int ln = lane & 31, hw = lane >> 5;
    int j0 = (w & 3) * 32;
    int nh = w >> 2;
#pragma unroll
    for (int i = 0; i < 16; i++) ap[i] = 0.f;
#pragma unroll
    for (int ks2 = 0; ks2 < 2; ks2++) {
        int ks = nh * 2 + ks2;
        unsigned pa[8], e[8];
#pragma unroll
        for (int j = 0; j < 8; j++) {
            int node = ks * 16 + 8 * hw + j;
            pa[j] = Ph[node * 32 + SWZ4(node, ln >> 2) + (ln & 3)];
            int col = j0 + ln;
            e[j] = As[node * 128 + SWZ4(node, col >> 2) + (col & 3)];
        }
        short8 a_hi, a_lo, b_hi, b_lo;
        permsplit(pa, a_hi, a_lo);
        permsplit(e, b_hi, b_lo);
        ap = __builtin_amdgcn_mfma_f32_32x32x16_bf16(a_hi, b_hi, ap, 0, 0, 0);
        ap = __builtin_amdgcn_mfma_f32_32x32x16_bf16(a_lo, b_hi, ap, 0, 0, 0);
        ap = __builtin_amdgcn_mfma_f32_32x32x16_bf16(a_hi, b_lo, ap, 0, 0, 0);
    }
}

// ---- PT reduce, wave-per-element: block j (0..2559), 64 lanes = 64 copies.
// One load per lane (640 KB L2-resident), 6-step shuffle reduce, lane-0 store.
__global__ void ptreduce_k(const float* __restrict__ PTc, float* __restrict__ PT) {
    int j = blockIdx.x;
    int c = threadIdx.x;
    float s = PTc[(size_t)c * 2560 + j];
    s += __shfl_xor(s, 32);
    s += __shfl_xor(s, 16);
    s += __shfl_xor(s, 8);
    s += __shfl_xor(s, 4);
    s += __shfl_xor(s, 2);
    s += __shfl_xor(s, 1);
    if (c == 0) PT[j] = s;
}

// ---- split lin_w (65536) + lower_w (512) into bf16 hi/lo. grid 258 x 256.
// Block 257 also zeroes G (400 f32) and RVh/RVl (16384 B) — replaces 2 memsets.
__global__ void wsplit_k(const float* __restrict__ lw, const float* __restrict__ low_w,
                         unsigned short* __restrict__ Wh, unsigned short* __restrict__ Wl,
                         unsigned short* __restrict__ LWh, unsigned short* __restrict__ LWl,
                         float* __restrict__ Gz, unsigned* __restrict__ RVz) {
    int i = blockIdx.x * 256 + threadIdx.x;
    float w;
    unsigned short *ph, *pl;
    int idx;
    if (i < 65536) { w = lw[i]; ph = Wh; pl = Wl; idx = i; }
    else           { w = low_w[i - 65536]; ph = LWh; pl = LWl; idx = i - 65536; }
    unsigned hb = rnbf(w);
    float fh = asf(hb << 16);
    unsigned lb = rnbf(w - fh);
    ph[idx] = (unsigned short)hb;
    pl[idx] = (unsigned short)lb;
    if (blockIdx.x == 257) {
        for (int z = threadIdx.x; z < 400; z += 256) Gz[z] = 0.f;
        for (int z = threadIdx.x; z < 4096; z += 256) RVz[z] = 0u;
    }
}

// ---- lift (GEMM tile) + inline y-bias fold + fused PT0 partial.
// 512 threads (8 waves), 4 blocks/CU (160 KiB LDS) -> 32 waves/CU occupancy cap.
// PT tail: 8-wave pt_mfma8 + LDS combine of node halves -> 2560 atomics/block.
__global__ __launch_bounds__(512, 8) void lift_k(const float* __restrict__ x,
                                                 const float* __restrict__ pos,
                                                 const float* __restrict__ phi,
                                                 const float* __restrict__ lw,
                                                 const float* __restrict__ lb,
                                                 const float* __restrict__ yg,
                                                 unsigned* __restrict__ hpk,
                                                 float* __restrict__ PTc) {
    __shared__ union {
        struct { float xs[64][21]; float Wc[20][132]; } a;
        unsigned As[64 * 128];
    } sm;
    __shared__ unsigned Ph[64 * 32];
    int t = threadIdx.x;
    int n0 = blockIdx.x * 64;
    if (t < 256) {
        int n = t >> 2, f4 = (t & 3) * 4;
        float4 xv = *(const float4*)(x + (size_t)(n0 + n) * 16 + f4);
        sm.a.xs[n][f4 + 0] = xv.x; sm.a.xs[n][f4 + 1] = xv.y;
        sm.a.xs[n][f4 + 2] = xv.z; sm.a.xs[n][f4 + 3] = xv.w;
    }
    if (t < 192) { int n = t / 3, d = t % 3; sm.a.xs[n][16 + d] = pos[(size_t)(n0 + n) * 3 + d]; }
    if (t < 64) sm.a.xs[t][19] = 1.f;
    for (int idx = t; idx < 2560; idx += 512) {
        int k = idx >> 7, j = idx & 127;
        float wv;
        if (k < 19) {
            wv = lw[j * 22 + k];
        } else {
            wv = lb[j] + yg[0] * lw[j * 22 + 19] + yg[1] * lw[j * 22 + 20]
                       + yg[2] * lw[j * 22 + 21];
        }
        sm.a.Wc[k][j] = wv;
    }
    for (int idx = t; idx < 2048; idx += 512) {
        int row = idx >> 5, kk = idx & 31;
        float pv = (kk < 20) ? phi[(size_t)(n0 + row) * 20 + kk] : 0.f;
        Ph[row * 32 + SWZ4(row, kk >> 2) + (kk & 3)] = packf(pv);
    }
    __syncthreads();
    // GEMM: 512 threads, each 4 rows (ty + 16*m) x 4 cols (tx*4..+3)
    int tx = t & 31, ty = t >> 5, i0 = tx * 4;
    float acc[4][4];
#pragma unroll
    for (int m = 0; m < 4; m++)
#pragma unroll
        for (int c = 0; c < 4; c++) acc[m][c] = 0.f;
#pragma unroll 4
    for (int k = 0; k < 20; k++) {
        float4 w = *(const float4*)&sm.a.Wc[k][i0];
#pragma unroll
        for (int m = 0; m < 4; m++) {
            float a = sm.a.xs[ty + 16 * m][k];
            acc[m][0] += a * w.x; acc[m][1] += a * w.y;
            acc[m][2] += a * w.z; acc[m][3] += a * w.w;
        }
    }
    __syncthreads();   // xs/Wc reads done before As overwrites the union
#pragma unroll
    for (int m = 0; m < 4; m++) {
        uint4 o;
        o.x = packf(acc[m][0]); o.y = packf(acc[m][1]);
        o.z = packf(acc[m][2]); o.w = packf(acc[m][3]);
        int row = ty + 16 * m;
        *(uint4*)&hpk[(size_t)(n0 + row) * 128 + i0] = o;
        *(uint4*)&sm.As[row * 128 + SWZ4(row, tx)] = o;
    }
    __syncthreads();
    floatx16 ap;
    pt_mfma8(sm.As, Ph, ap, t);
    int lane = t & 63, w = t >> 6;
    int ln = lane & 31, hw = lane >> 5;
    int j0 = (w & 3) * 32, nh = w >> 2;
    __syncthreads();            // all As/Ph reads done before overlay
    float* PTs = (float*)sm.As; // 10 KB scratch overlay (As dead now)
    if (nh == 1) {
#pragma unroll
        for (int r = 0; r < 16; r++) {
            int mode = (r & 3) + 8 * (r >> 2) + 4 * hw;
            if (mode < 20) PTs[mode * 128 + j0 + ln] = ap[r];
        }
    }
    __syncthreads();
    if (nh == 0) {
        float* blk = PTc + (size_t)(blockIdx.x & 63) * 2560;
#pragma unroll
        for (int r = 0; r < 16; r++) {
            int mode = (r & 3) + 8 * (r >> 2) + 4 * hw;
            if (mode < 20) {
                int idx = mode * 128 + j0 + ln;
                unsafeAtomicAdd(&blk[idx], ap[r] + PTs[idx]);
            }
        }
    }
}

// ---- G = phi^T phi  (20x20). Grid-stride over tiles; widened grid halves depth.
__global__ void gram_k(const float* __restrict__ phi, float* __restrict__ G) {
    __shared__ float ph[64 * 20];
    int t = threadIdx.x;
    int i0 = t / 20, j0 = t % 20;
    int p1 = t + 256;
    int i1 = p1 / 20, j1 = p1 % 20;
    float a0 = 0.f, a1 = 0.f;
    for (int tile = blockIdx.x; tile < NT; tile += gridDim.x) {
        const float* src = phi + tile * 1280;
        for (int idx = t; idx < 1280; idx += 256) ph[idx] = src[idx];
        __syncthreads();
        for (int n = 0; n < 64; n++) {
            const float* r = ph + n * 20;
            a0 += r[i0] * r[j0];
            if (p1 < 400) a1 += r[i1] * r[j1];
        }
        __syncthreads();
    }
    unsafeAtomicAdd(&G[t], a0);
    if (p1 < 400) unsafeAtomicAdd(&G[p1], a1);
}

// ---- Gauss-Jordan inverse of 20x20
__global__ void ginv_k(const float* __restrict__ G, float* __restrict__ Gi) {
    __shared__ float A[20][40];
    __shared__ float colp[20];
    __shared__ float piv;
    int t = threadIdx.x;
    for (int idx = t; idx < 400; idx += 64) {
        int r = idx / 20, c = idx % 20;
        A[r][c] = G[idx];
        A[r][c + 20] = (r == c) ? 1.f : 0.f;
    }
    __syncthreads();
    for (int p = 0; p < 20; p++) {
        if (t == 0) piv = 1.f / A[p][p];
        __syncthreads();
        for (int c = t; c < 40; c += 64) A[p][c] *= piv;
        __syncthreads();
        if (t < 20) colp[t] = A[t][p];
        __syncthreads();
        for (int e = t; e < 800; e += 64) {
            int r = e / 40, c = e % 40;
            if (r != p) A[r][c] -= colp[r] * A[p][c];
        }
        __syncthreads();
    }
    for (int idx = t; idx < 400; idx += 64) {
        int r = idx / 20, c = idx % 20;
        Gi[idx] = A[r][c + 20];
    }
}

// ---- v[k] = Gi[k] @ PT; RV = kernel[l][k] @ v[k]. Widened: grid (20, 8) x 256.
// kern loads hoisted ABOVE the zero/v phase so cold-HBM latency hides under it.
// Also zeros its 4 KB slice of PTc (replaces the per-layer memset dispatch).
__global__ void rv_k(const float* __restrict__ Gi, const float* __restrict__ PT,
                     const float* __restrict__ kern_l,
                     unsigned short* __restrict__ RVh, unsigned short* __restrict__ RVl,
                     float* __restrict__ ptz) {
    __shared__ __align__(16) float v[128];
    int k = blockIdx.x;
    int t = threadIdx.x;
    int il = t >> 4, seg = t & 15;
    int i = blockIdx.y * 16 + il;
    const float* kr = kern_l + (size_t)(k * 128 + i) * 128 + seg * 8;
    float4 ka = *(const float4*)kr;        // issue early: cold HBM
    float4 kb = *(const float4*)(kr + 4);
    // zero this block's slice of PTc: 160 blocks x 1024 floats = 64 copies x 2560
    {
        float4 z = { 0.f, 0.f, 0.f, 0.f };
        int s = k * 8 + blockIdx.y;
        *(float4*)&ptz[(size_t)s * 1024 + t * 4] = z;
    }
    if (t < 128) {
        const float* gr = Gi + k * 20;
        float s = 0.f;
#pragma unroll
        for (int m = 0; m < 20; m++) s += gr[m] * PT[m * 128 + t];
        v[t] = s;
    }
    __syncthreads();
    const float* vk = v + seg * 8;
    float4 va = *(const float4*)vk;
    float4 vb = *(const float4*)(vk + 4);
    float acc = ka.x * va.x + ka.y * va.y + ka.z * va.z + ka.w * va.w
              + kb.x * vb.x + kb.y * vb.y + kb.z * vb.z + kb.w * vb.w;
    acc += __shfl_xor(acc, 8);
    acc += __shfl_xor(acc, 4);
    acc += __shfl_xor(acc, 2);
    acc += __shfl_xor(acc, 1);
    if (seg == 0) {
        unsigned hb = rnbf(acc);
        float fh = asf(hb << 16);
        unsigned lb = rnbf(acc - fh);
        RVh[i * 32 + k] = (unsigned short)hb;
        RVl[i * 32 + k] = (unsigned short)lb;
    }
}

// ---- MFMA update: 64-row tile, 512 threads, 4 blocks/CU (160 KiB LDS).
// SPLIT-PLANE LDS: h and phi tiles as separate hi/lo ushort planes (direct b128 reads).
// Each wave owns one 32x32 output quadrant: rows (w>>2)*32, cols (w&3)*32.
// h = elu(h@W^T + phi@RV).
// l<3: re-stash, then waves 0-3 compute FULL-K PT directly + atomics (no combine
//      barriers; waves 4-7 retire early). Same 2560 atomics/block as before.
// l=3 (outp): re-stash + fused MFMA lower epilogue, skip h store.
__global__ __launch_bounds__(512, 8) void update_k(unsigned* __restrict__ hpk,
                                                   const float* __restrict__ phi,
                                                   const unsigned short* __restrict__ Wh,
                                                   const unsigned short* __restrict__ Wl,
                                                   const unsigned short* __restrict__ RVh,
                                                   const unsigned short* __restrict__ RVl,
                                                   float* __restrict__ ptn,
                                                   const unsigned short* __restrict__ LWh,
                                                   const unsigned short* __restrict__ LWl,
                                                   const float* __restrict__ low_b,
                                                   float* __restrict__ outp) {
    // 16384*2 + 4096*2 = 40960 B
    __shared__ __align__(16) unsigned short Ash[64 * 128];
    __shared__ __align__(16) unsigned short Asl[64 * 128];
    __shared__ __align__(16) unsigned short Phh[64 * 32];
    __shared__ __align__(16) unsigned short Phl[64 * 32];
    int t = threadIdx.x;
    int n0 = blockIdx.x * 64;
    // ---- stage packed h -> split planes (swizzled), packed phi -> split planes
    for (int idx = t; idx < 2048; idx += 512) {
        int row = idx >> 5, g = idx & 31;          // g: dword group of 4 cols
        uint4 v = *(const uint4*)(hpk + (size_t)(n0 + row) * 128 + g * 4);
        uint2 hv, lv;
        hv.x = __builtin_amdgcn_perm(v.y, v.x, 0x05040100u);
        hv.y = __builtin_amdgcn_perm(v.w, v.z, 0x05040100u);
        lv.x = __builtin_amdgcn_perm(v.y, v.x, 0x07060302u);
        lv.y = __builtin_amdgcn_perm(v.w, v.z, 0x07060302u);
        int base = row * 128 + (((g >> 1) ^ (row & 7)) << 3) + (g & 1) * 4;
        *(uint2*)&Ash[base] = hv;
        *(uint2*)&Asl[base] = lv;
    }
    for (int idx = t; idx < 2048; idx += 512) {
        int row = idx >> 5, kk = idx & 31;
        float pv = (kk < 20) ? phi[(size_t)(n0 + row) * 20 + kk] : 0.f;
        unsigned hb = rnbf(pv);
        float fh = asf(hb << 16);
        unsigned lb = rnbf(pv - fh);
        int pi = row * 32 + (((kk >> 3) ^ (row & 3)) << 3) + (kk & 7);
        Phh[pi] = (unsigned short)hb;
        Phl[pi] = (unsigned short)lb;
    }
    __syncthreads();

    int lane = t & 63, w = t >> 6;
    int ln = lane & 31, hw = lane >> 5;
    int r0 = (w >> 2) * 32, ct0 = (w & 3) * 32;
    int arow = r0 + ln;

    floatx16 acc;
#pragma unroll
    for (int i = 0; i < 16; i++) acc[i] = 0.f;

    const unsigned short* whp = Wh + (size_t)(ct0 + ln) * 128 + 8 * hw;
    const unsigned short* wlp = Wl + (size_t)(ct0 + ln) * 128 + 8 * hw;
    const unsigned short* ahb = Ash + arow * 128;
    const unsigned short* alb = Asl + arow * 128;
    int r7 = arow & 7;

    // ---- main K-loop (8 steps of 16): A-frags are direct b128 reads, zero perms
#pragma unroll
    for (int ks = 0; ks < 8; ks++) {
        int k0 = ks * 16;
        int gh = ((2 * ks + hw) ^ r7) << 3;
        short8 a_hi = __builtin_bit_cast(short8, *(const uint4*)(ahb + gh));
        short8 a_lo = __builtin_bit_cast(short8, *(const uint4*)(alb + gh));
        short8 bh = __builtin_bit_cast(short8, *(const uint4*)(whp + k0));
        short8 bl = __builtin_bit_cast(short8, *(const uint4*)(wlp + k0));
        acc = __builtin_amdgcn_mfma_f32_32x32x16_bf16(a_hi, bh, acc, 0, 0, 0);
        acc = __builtin_amdgcn_mfma_f32_32x32x16_bf16(a_lo, bh, acc, 0, 0, 0);
        acc = __builtin_amdgcn_mfma_f32_32x32x16_bf16(a_hi, bl, acc, 0, 0, 0);
    }

    // ---- phi @ RV: 2 more k-steps, direct b128 reads from phi planes
    const unsigned short* phb = Phh + arow * 32;
    const unsigned short* plb = Phl + arow * 32;
    int r3 = arow & 3;
#pragma unroll
    for (int ks = 0; ks < 2; ks++) {
        int k0 = ks * 16;
        int gp = ((2 * ks + hw) ^ r3) << 3;
        short8 a_hi = __builtin_bit_cast(short8, *(const uint4*)(phb + gp));
        short8 a_lo = __builtin_bit_cast(short8, *(const uint4*)(plb + gp));
        short8 bh = __builtin_bit_cast(short8, *(const uint4*)(RVh + (size_t)(ct0 + ln) * 32 + k0 + 8 * hw));
        short8 bl = __builtin_bit_cast(short8, *(const uint4*)(RVl + (size_t)(ct0 + ln) * 32 + k0 + 8 * hw));
        acc = __builtin_amdgcn_mfma_f32_32x32x16_bf16(a_hi, bh, acc, 0, 0, 0);
        acc = __builtin_amdgcn_mfma_f32_32x32x16_bf16(a_lo, bh, acc, 0, 0, 0);
        acc = __builtin_amdgcn_mfma_f32_32x32x16_bf16(a_hi, bl, acc, 0, 0, 0);
    }

    // ---- elu + pack; persist h unless this is the fused-output layer
    unsigned p0[16];
#pragma unroll
    for (int r = 0; r < 16; r++) {
        float v0 = acc[r];
        v0 = v0 > 0.f ? v0 : __expf(v0) - 1.f;
        p0[r] = packf(v0);
    }
    if (!outp) {
#pragma unroll
        for (int r = 0; r < 16; r++) {
            int row = (r & 3) + 8 * (r >> 2) + 4 * hw;
            hpk[(size_t)(n0 + r0 + row) * 128 + ct0 + ln] = p0[r];
        }
    }
    if (ptn || outp) {
        __syncthreads();   // all old-h LDS reads done
        // re-stash new h into the split planes (swizzled scalar u16 writes)
#pragma unroll
        for (int r = 0; r < 16; r++) {
            int row = r0 + (r & 3) + 8 * (r >> 2) + 4 * hw;
            int c0 = ct0 + ln;
            int si = row * 128 + (((c0 >> 3) ^ (row & 7)) << 3) + (c0 & 7);
            Ash[si] = (unsigned short)p0[r];
            Asl[si] = (unsigned short)(p0[r] >> 16);
        }
        __syncthreads();
        if (outp) {
            // MFMA lower: out = h @ lower_w^T + b. Waves 0-3 only:
            // r0o=(w>>1)*32 rows, kh=(w&1) k-half. B rows (outputs) 0-3, rows >=4 zero.
            float* scr = (float*)Phh;   // 1 KB scratch (phi planes dead at l=3)
            int r0o = (w >> 1) * 32, kh = w & 1;
            int arow2 = r0o + ln;
            const unsigned short* ah2 = Ash + arow2 * 128;
            const unsigned short* al2 = Asl + arow2 * 128;
            int rr7 = arow2 & 7;
            floatx16 ap;
#pragma unroll
            for (int i = 0; i < 16; i++) ap[i] = 0.f;
            if (w < 4) {
#pragma unroll
                for (int kk = 0; kk < 4; kk++) {
                    int ks = kh * 4 + kk;
                    int gh = ((2 * ks + hw) ^ rr7) << 3;
                    short8 a_hi = __builtin_bit_cast(short8, *(const uint4*)(ah2 + gh));
                    short8 a_lo = __builtin_bit_cast(short8, *(const uint4*)(al2 + gh));
                    short8 bh = { 0, 0, 0, 0, 0, 0, 0, 0 };
                    short8 bl = { 0, 0, 0, 0, 0, 0, 0, 0 };
                    if (ln < 4) {
                        bh = __builtin_bit_cast(short8, *(const uint4*)(LWh + ln * 128 + ks * 16 + 8 * hw));
                        bl = __builtin_bit_cast(short8, *(const uint4*)(LWl + ln * 128 + ks * 16 + 8 * hw));
                    }
                    ap = __builtin_amdgcn_mfma_f32_32x32x16_bf16(a_hi, bh, ap, 0, 0, 0);
                    ap = __builtin_amdgcn_mfma_f32_32x32x16_bf16(a_lo, bh, ap, 0, 0, 0);
                    ap = __builtin_amdgcn_mfma_f32_32x32x16_bf16(a_hi, bl, ap, 0, 0, 0);
                }
            }
            if (w < 4 && kh == 1 && ln < 4) {
#pragma unroll
                for (int r = 0; r < 16; r++) {
                    int row = (r & 3) + 8 * (r >> 2) + 4 * hw;
                    scr[(w >> 1) * 128 + row * 4 + ln] = ap[r];
                }
            }
            __syncthreads();
            if (w < 4 && kh == 0 && ln < 4) {
                float b = low_b[ln];
#pragma unroll
                for (int r = 0; r < 16; r++) {
                    int row = (r & 3) + 8 * (r >> 2) + 4 * hw;
                    float s = ap[r] + scr[(w >> 1) * 128 + row * 4 + ln] + b;
                    outp[(size_t)(n0 + r0o + row) * 4 + ln] = s;
                }
            }
        } else if (w < 4) {
            // ---- PT partial: waves 0-3 FULL-K (ks 0..3), direct atomics.
            // Exact round-3/6 gather math with the node-half split removed.
            int j0 = w * 32;
            floatx16 ap;
#pragma unroll
            for (int i = 0; i < 16; i++) ap[i] = 0.f;
#pragma unroll
            for (int ks = 0; ks < 4; ks++) {
                unsigned short ah[8], al[8], bh[8], bl[8];
#pragma unroll
                for (int j = 0; j < 8; j++) {
                    int node = ks * 16 + 8 * hw + j;
                    int pi = node * 32 + (((ln >> 3) ^ (node & 3)) << 3) + (ln & 7);
                    ah[j] = Phh[pi]; al[j] = Phl[pi];
                    int col = j0 + ln;
                    int si = node * 128 + (((col >> 3) ^ (node & 7)) << 3) + (col & 7);
                    bh[j] = Ash[si]; bl[j] = Asl[si];
                }
                uint4 qa, qb, qc, qd;
                qa.x = (unsigned)ah[0] | ((unsigned)ah[1] << 16);
                qa.y = (unsigned)ah[2] | ((unsigned)ah[3] << 16);
                qa.z = (unsigned)ah[4] | ((unsigned)ah[5] << 16);
                qa.w = (unsigned)ah[6] | ((unsigned)ah[7] << 16);
                qb.x = (unsigned)al[0] | ((unsigned)al[1] << 16);
                qb.y = (unsigned)al[2] | ((unsigned)al[3] << 16);
                qb.z = (unsigned)al[4] | ((unsigned)al[5] << 16);
                qb.w = (unsigned)al[6] | ((unsigned)al[7] << 16);
                qc.x = (unsigned)bh[0] | ((unsigned)bh[1] << 16);
                qc.y = (unsigned)bh[2] | ((unsigned)bh[3] << 16);
                qc.z = (unsigned)bh[4] | ((unsigned)bh[5] << 16);
                qc.w = (unsigned)bh[6] | ((unsigned)bh[7] << 16);
                qd.x = (unsigned)bl[0] | ((unsigned)bl[1] << 16);
                qd.y = (unsigned)bl[2] | ((unsigned)bl[3] << 16);
                qd.z = (unsigned)bl[4] | ((unsigned)bl[5] << 16);
                qd.w = (unsigned)bl[6] | ((unsigned)bl[7] << 16);
                short8 a_hi = __builtin_bit_cast(short8, qa);
                short8 a_lo = __builtin_bit_cast(short8, qb);
                short8 b_hi = __builtin_bit_cast(short8, qc);
                short8 b_lo = __builtin_bit_cast(short8, qd);
                ap = __builtin_amdgcn_mfma_f32_32x32x16_bf16(a_hi, b_hi, ap, 0, 0, 0);
                ap = __builtin_amdgcn_mfma_f32_32x32x16_bf16(a_lo, b_hi, ap, 0, 0, 0);
                ap = __builtin_amdgcn_mfma_f32_32x32x16_bf16(a_hi, b_lo, ap, 0, 0, 0);
            }
            float* blk = ptn + (size_t)(blockIdx.x & 63) * 2560;
#pragma unroll
            for (int r = 0; r < 16; r++) {
                int mode = (r & 3) + 8 * (r >> 2) + 4 * hw;
                if (mode < 20) unsafeAtomicAdd(&blk[mode * 128 + j0 + ln], ap[r]);
            }
        }
    }
}

extern "C" void kernel_launch(void* const* d_in, const int* in_sizes, int n_in,
                              void* d_out, int out_size, void* d_ws, size_t ws_size,
                              hipStream_t stream) {
    (void)in_sizes; (void)n_in; (void)out_size; (void)ws_size;
    const float* x       = (const float*)d_in[0];
    const float* pos     = (const float*)d_in[1];
    const float* y       = (const float*)d_in[2];
    const float* phi     = (const float*)d_in[3];
    const float* lift_w  = (const float*)d_in[4];
    const float* lift_b  = (const float*)d_in[5];
    const float* lin_w   = (const float*)d_in[6];
    const float* kern    = (const float*)d_in[7];
    const float* lower_w = (const float*)d_in[8];
    const float* lower_b = (const float*)d_in[9];
    float* out = (float*)d_out;

    char* ws = (char*)d_ws;
    unsigned* hpk = (unsigned*)ws;                       // 102,400,000 B
    size_t off = (size_t)Nn * 128 * 4;
    float* b2  = (float*)(ws + off);       off += 512;    // unused, layout kept
    float* G   = (float*)(ws + off);       off += 1600;
    float* Gi  = (float*)(ws + off);       off += 1600;
    off = (off + 15) & ~(size_t)15;
    float* PT  = (float*)(ws + off);       off += 10240;
    float* PTc = (float*)(ws + off);       off += 64 * 2560 * 4;   // 640 KB
    unsigned short* W_hi = (unsigned short*)(ws + off);  off += 131072;
    unsigned short* W_lo = (unsigned short*)(ws + off);  off += 131072;
    unsigned short* RVh  = (unsigned short*)(ws + off);  off += 8192;
    unsigned short* RVl  = (unsigned short*)(ws + off);  off += 8192;
    unsigned short* LWh  = (unsigned short*)(ws + off);  off += 1024;
    unsigned short* LWl  = (unsigned short*)(ws + off);  off += 1024;
    (void)b2;

    hipMemsetAsync(PTc, 0, 64 * 2560 * 4, stream);
    wsplit_k<<<258, 256, 0, stream>>>(lin_w, lower_w, W_hi, W_lo, LWh, LWl,
                                      G, (unsigned*)RVh);
    lift_k<<<NT, 512, 0, stream>>>(x, pos, phi, lift_w, lift_b, y, hpk, PTc);
    gram_k<<<512, 256, 0, stream>>>(phi, G);
    ginv_k<<<1, 64, 0, stream>>>(G, Gi);
    ptreduce_k<<<2560, 64, 0, stream>>>(PTc, PT);

    for (int l = 0; l < 4; l++) {
        // rv also zeroes PTc for the coming update (ptreduce for prev layer is done)
        rv_k<<<dim3(20, 8), 256, 0, stream>>>(Gi, PT, kern + (size_t)l * 20 * 128 * 128,
                                              RVh, RVl, PTc);
        float* ptc = (l < 3) ? PTc : (float*)nullptr;
        update_k<<<NT, 512, 0, stream>>>(hpk, phi, W_hi + (size_t)l * 16384,
                                         W_lo + (size_t)l * 16384, RVh, RVl, ptc,
                                         LWh, LWl, lower_b,
                                         (l == 3) ? out : (float*)nullptr);
        if (ptc) ptreduce_k<<<2560, 64, 0, stream>>>(PTc, PT);
    }
}